// Round 5
// baseline (1116.409 us; speedup 1.0000x reference)
//
#include <hip/hip_runtime.h>

#define HW 80
#define NPIX 6400
#define NF 64
#define NB 8
#define NLIN 4624
#define NL2 2312

// ---------------- generic jax-style bilinear (triangle, antialias) taps ----------------
__device__ __forceinline__ int resize_taps(int o, int n_in, int n_out, int* i0, float* w) {
  float inv = (float)n_in / (float)n_out;
  float ks = inv > 1.f ? inv : 1.f;          // antialias: kernel scale = max(in/out, 1)
  float sf = ((float)o + 0.5f) * inv - 0.5f;
  int lo = (int)ceilf(sf - ks);
  int hi = (int)floorf(sf + ks);
  if (lo < 0) lo = 0;
  if (hi > n_in - 1) hi = n_in - 1;
  int n = hi - lo + 1;
  if (n > 3) n = 3;
  float tot = 0.f;
  #pragma unroll
  for (int k = 0; k < 3; ++k) {
    if (k < n) {
      float d = fabsf((float)(lo + k) - sf) / ks;
      float ww = 1.f - d; if (ww < 0.f) ww = 0.f;
      w[k] = ww; tot += ww;
    } else w[k] = 0.f;
  }
  float r = 1.f / tot;
  #pragma unroll
  for (int k = 0; k < 3; ++k) w[k] *= r;
  *i0 = lo;
  return n;
}

// ---------------- encoder: 3x(avg3+tanh+max3) + resize 68->80, one WG per plane ----------------
// blocks 0..511: planes of x (8,64,80,80). blocks 512..519: channel-max plane of x per batch.
__global__ __launch_bounds__(256) void encoder_kernel(const float* __restrict__ x,
                                                      float* __restrict__ x_enc,
                                                      float* __restrict__ x1_enc) {
  __shared__ float b0[6400];
  __shared__ float b1[6084];
  int p = blockIdx.x, t = threadIdx.x;
  if (p < 512) {
    const float* pl = x + (size_t)p * NPIX;
    for (int i = t; i < NPIX; i += 256) b0[i] = pl[i];
  } else {
    const float* pb = x + (size_t)(p - 512) * NF * NPIX;
    for (int i = t; i < NPIX; i += 256) {
      float m = pb[i];
      for (int f = 1; f < NF; ++f) m = fmaxf(m, pb[f * NPIX + i]);
      b0[i] = m;
    }
  }
  __syncthreads();
  int sz = 80;
  for (int L = 0; L < 3; ++L) {
    int s1 = sz - 2;
    for (int i = t; i < s1 * s1; i += 256) {
      int r = i / s1, c = i % s1;
      float s = 0.f;
      #pragma unroll
      for (int dr = 0; dr < 3; ++dr)
        #pragma unroll
        for (int dc = 0; dc < 3; ++dc) s += b0[(r + dr) * sz + (c + dc)];
      b1[i] = tanhf(s * (1.f / 9.f));
    }
    __syncthreads();
    int s2 = s1 - 2;
    for (int i = t; i < s2 * s2; i += 256) {
      int r = i / s2, c = i % s2;
      float m = -1e30f;
      #pragma unroll
      for (int dr = 0; dr < 3; ++dr)
        #pragma unroll
        for (int dc = 0; dc < 3; ++dc) m = fmaxf(m, b1[(r + dr) * s1 + (c + dc)]);
      b0[i] = m;
    }
    __syncthreads();
    sz = s2;
  }
  // sz == 68; bilinear resize 68 -> 80 (upsample, 2-3 taps)
  float* dst = (p < 512) ? (x_enc + (size_t)p * NPIX) : (x1_enc + (size_t)(p - 512) * NPIX);
  for (int i = t; i < NPIX; i += 256) {
    int r = i / HW, c = i % HW;
    int r0, c0; float wr[3], wc[3];
    int nr = resize_taps(r, 68, 80, &r0, wr);
    int nc = resize_taps(c, 68, 80, &c0, wc);
    float v = 0.f;
    for (int a = 0; a < nr; ++a) {
      float rv = 0.f;
      for (int bq = 0; bq < nc; ++bq) rv += wc[bq] * b0[(r0 + a) * 68 + (c0 + bq)];
      v += wr[a] * rv;
    }
    dst[i] = v;
  }
}

// ---------------- MSB: per-plane conv2x2->81^2, conv4x4->79^2, bn+tanh, resize->80, 1x1 mix, bn.
// chan path (blocks 0..511): fused 16x16 block-mean -> P (8,64,25). spat path (512..519): write plane.
__global__ __launch_bounds__(256) void msb_kernel(
    const float* __restrict__ x_enc, const float* __restrict__ x1_enc,
    const float* mc_w1, const float* mc_g1, const float* mc_b1,
    const float* mc_w2, const float* mc_g2, const float* mc_b2,
    const float* mc_wd, const float* mc_gd, const float* mc_bd,
    const float* ms_w1, const float* ms_g1, const float* ms_b1,
    const float* ms_w2, const float* ms_g2, const float* ms_b2,
    const float* ms_wd, const float* ms_gd, const float* ms_bd,
    float* __restrict__ P, float* __restrict__ spat_msb) {
  __shared__ float xin[6400];
  __shared__ float t1[6561];   // 81*81
  __shared__ float t2[6241];   // 79*79
  __shared__ float red[200];
  int p = blockIdx.x, t = threadIdx.x;
  bool chan_path = (p < 512);
  const float* src = chan_path ? (x_enc + (size_t)p * NPIX) : (x1_enc + (size_t)(p - 512) * NPIX);
  const float* w1p = chan_path ? mc_w1 : ms_w1;
  const float* w2p = chan_path ? mc_w2 : ms_w2;
  const float* wdp = chan_path ? mc_wd : ms_wd;
  const float rs = rsqrtf(1.f + 1e-5f);
  float s1 = (chan_path ? mc_g1[0] : ms_g1[0]) * rs;
  float o1 = (chan_path ? mc_b1[0] : ms_b1[0]);
  float s2 = (chan_path ? mc_g2[0] : ms_g2[0]) * rs;
  float o2 = (chan_path ? mc_b2[0] : ms_b2[0]);
  float sd = (chan_path ? mc_gd[0] : ms_gd[0]) * rs;
  float od = (chan_path ? mc_bd[0] : ms_bd[0]);
  float wd0 = wdp[0], wd1 = wdp[1];
  float W1[4], W2[16];
  #pragma unroll
  for (int k = 0; k < 4; ++k) W1[k] = w1p[k];
  #pragma unroll
  for (int k = 0; k < 16; ++k) W2[k] = w2p[k];

  for (int i = t; i < NPIX; i += 256) xin[i] = src[i];
  __syncthreads();

  for (int i = t; i < 6561; i += 256) {
    int r = i / 81 - 1, c = i % 81 - 1;
    float s = 0.f;
    #pragma unroll
    for (int a = 0; a < 2; ++a) {
      int rr = r + a; if (rr < 0 || rr >= 80) continue;
      #pragma unroll
      for (int b = 0; b < 2; ++b) {
        int cc = c + b; if (cc < 0 || cc >= 80) continue;
        s += W1[a * 2 + b] * xin[rr * 80 + cc];
      }
    }
    t1[i] = tanhf(s * s1 + o1);
  }
  for (int i = t; i < 6241; i += 256) {
    int r = i / 79 - 1, c = i % 79 - 1;
    float s = 0.f;
    #pragma unroll
    for (int a = 0; a < 4; ++a) {
      int rr = r + a; if (rr < 0 || rr >= 80) continue;
      #pragma unroll
      for (int b = 0; b < 4; ++b) {
        int cc = c + b; if (cc < 0 || cc >= 80) continue;
        s += W2[a * 4 + b] * xin[rr * 80 + cc];
      }
    }
    t2[i] = tanhf(s * s2 + o2);
  }
  __syncthreads();

  // final 80x80: resize t1 (81->80, antialiased 3-tap) and t2 (79->80), mix, bn
  float vals[25];
  #pragma unroll
  for (int k = 0; k < 25; ++k) {
    int i = t + k * 256;
    int r = i / HW, c = i % HW;
    int r0, c0; float wr[3], wc[3];
    int nr = resize_taps(r, 81, 80, &r0, wr);
    int nc = resize_taps(c, 81, 80, &c0, wc);
    float v1 = 0.f;
    for (int a = 0; a < nr; ++a) {
      float rv = 0.f;
      for (int bq = 0; bq < nc; ++bq) rv += wc[bq] * t1[(r0 + a) * 81 + (c0 + bq)];
      v1 += wr[a] * rv;
    }
    nr = resize_taps(r, 79, 80, &r0, wr);
    nc = resize_taps(c, 79, 80, &c0, wc);
    float v2 = 0.f;
    for (int a = 0; a < nr; ++a) {
      float rv = 0.f;
      for (int bq = 0; bq < nc; ++bq) rv += wc[bq] * t2[(r0 + a) * 79 + (c0 + bq)];
      v2 += wr[a] * rv;
    }
    vals[k] = (v1 * wd0 + v2 * wd1) * sd + od;
  }
  if (chan_path) {
    #pragma unroll
    for (int k = 0; k < 25; ++k) xin[t + k * 256] = vals[k];
    __syncthreads();
    // 16x16 block means -> P[p*25 + bin]
    if (t < 200) {
      int bin = t >> 3, sub = t & 7;
      int ki = bin / 5, kj = bin % 5;
      int r0 = ki * 16 + sub * 2, c0 = kj * 16;
      float s = 0.f;
      for (int rr = r0; rr < r0 + 2; ++rr)
        for (int cc = c0; cc < c0 + 16; ++cc) s += xin[rr * 80 + cc];
      red[t] = s;
    }
    __syncthreads();
    if (t < 25) {
      float s = 0.f;
      #pragma unroll
      for (int k = 0; k < 8; ++k) s += red[t * 8 + k];
      P[(size_t)p * 25 + t] = s * (1.f / 256.f);
    }
  } else {
    float* dst = spat_msb + (size_t)(p - 512) * NPIX;
    #pragma unroll
    for (int k = 0; k < 25; ++k) dst[t + k * 256] = vals[k];
  }
}

// ---------------- xs = sum over f of x_enc ----------------
__global__ __launch_bounds__(256) void fsum_kernel(const float* __restrict__ x_enc, float* __restrict__ xs) {
  int idx = blockIdx.x * 256 + threadIdx.x;
  if (idx >= NB * NPIX) return;
  int b = idx / NPIX, pix = idx % NPIX;
  const float* p = x_enc + (size_t)b * NF * NPIX + pix;
  float s = 0.f;
  for (int f = 0; f < NF; ++f) s += p[f * NPIX];
  xs[idx] = s;
}

// ---------------- spat_filter (25-softmax) fused with spat_o patch dot ----------------
__global__ __launch_bounds__(256) void spat_kernel(const float* __restrict__ spat_msb,
                                                   const float* __restrict__ xs,
                                                   const float* __restrict__ sf_w,
                                                   const float* __restrict__ sf_b,
                                                   float* __restrict__ ybuf /* (8,2,6400) */) {
  int idx = blockIdx.x * 256 + threadIdx.x;
  if (idx >= NB * NPIX) return;
  int b = idx / NPIX, pix = idx % NPIX;
  int h = pix / HW, w = pix % HW;
  float v = spat_msb[idx];
  float lg[25];
  float mx = -1e30f;
  #pragma unroll
  for (int c = 0; c < 25; ++c) {
    lg[c] = v * (sf_w[c] + 1.f) + sf_b[c];
    mx = fmaxf(mx, lg[c]);
  }
  float den = 0.f;
  #pragma unroll
  for (int c = 0; c < 25; ++c) { lg[c] = expf(lg[c] - mx); den += lg[c]; }
  const float* xp = xs + (size_t)b * NPIX;
  float acc = 0.f;
  #pragma unroll
  for (int i = 0; i < 5; ++i) {
    int r = h + i - 2; if (r < 0 || r >= HW) continue;
    #pragma unroll
    for (int j = 0; j < 5; ++j) {
      int c2 = w + j - 2; if (c2 < 0 || c2 >= HW) continue;
      acc += lg[i * 5 + j] * xp[r * HW + c2];
    }
  }
  ybuf[(size_t)b * 2 * NPIX + pix] = acc / den;
}

// ---------------- chan_filter tail: P (8,64,25) -> cf (8,64,25) ----------------
__global__ __launch_bounds__(64) void cf_mix_kernel(const float* __restrict__ P,
                                                    const float* __restrict__ cw_w,
                                                    const float* __restrict__ cw_b,
                                                    const float* __restrict__ dw,
                                                    const float* __restrict__ db,
                                                    float* __restrict__ cf) {
  __shared__ float tmp[64];
  int blk = blockIdx.x;            // 200 = b*25 + bin
  int b = blk / 25, bin = blk % 25;
  int f = threadIdx.x;             // 64 = one wave
  float mw = 0.f, mb = 0.f;
  #pragma unroll
  for (int k = 0; k < 16; ++k) { mw += cw_w[k]; mb += cw_b[k]; }
  mw *= (1.f / 16.f); mb *= (1.f / 16.f);
  float pv = P[((size_t)b * 64 + f) * 25 + bin];
  float s = pv;
  #pragma unroll
  for (int off = 32; off; off >>= 1) s += __shfl_down(s, off);
  float Pm = __shfl(s, 0) * (1.f / 64.f);
  tmp[f] = pv * mw + mb + Pm;
  __syncthreads();
  const float* dwr = dw + f * 64;
  float acc = db[f];
  for (int k = 0; k < 64; ++k) acc += dwr[k] * tmp[k];
  cf[((size_t)b * 64 + f) * 25 + bin] = acc;
}

// ---------------- chan_o: per-batch per-channel 5x5 dynamic conv, summed over f ----------------
__global__ __launch_bounds__(320) void chan_conv_kernel(const float* __restrict__ x_enc,
                                                        const float* __restrict__ cf,
                                                        float* __restrict__ ybuf) {
  __shared__ float cfl[1600];
  int blk = blockIdx.x;          // 160 = b*20 + rowtile
  int b = blk / 20, rt = blk % 20;
  int t = threadIdx.x;           // 320 = 4 rows x 80
  for (int i = t; i < 1600; i += 320) cfl[i] = cf[(size_t)b * 1600 + i];
  __syncthreads();
  int r = rt * 4 + t / 80, c = t % 80;
  const float* xb = x_enc + (size_t)b * NF * NPIX;
  float acc = 0.f;
  for (int f = 0; f < NF; ++f) {
    const float* xp = xb + (size_t)f * NPIX;
    const float* cp = cfl + f * 25;
    #pragma unroll
    for (int i = 0; i < 5; ++i) {
      int rr = r + i - 2; if (rr < 0 || rr >= HW) continue;
      #pragma unroll
      for (int j = 0; j < 5; ++j) {
        int cc = c + j - 2; if (cc < 0 || cc >= HW) continue;
        acc += cp[i * 5 + j] * xp[rr * HW + cc];
      }
    }
  }
  ybuf[(size_t)b * 2 * NPIX + NPIX + r * HW + c] = acc;
}

// ---------------- decoder conv1 (2->6, 5x5 valid) + relu + maxpool2 ----------------
__global__ __launch_bounds__(256) void dconv1_kernel(const float* __restrict__ ybuf,
                                                     const float* __restrict__ dp_w,
                                                     const float* __restrict__ dr_w,
                                                     const float* __restrict__ bias,
                                                     float* __restrict__ d1) {
  int idx = blockIdx.x * 256 + threadIdx.x;
  if (idx >= 2 * NB * 6 * 38 * 38) return;
  int d = idx / (NB * 6 * 1444);
  int rem = idx % (NB * 6 * 1444);
  int b = rem / (6 * 1444);
  int rem2 = rem % (6 * 1444);
  int oc = rem2 / 1444, pp = rem2 % 1444;
  int py = pp / 38, px = pp % 38;
  const float* W = (d ? dr_w : dp_w) + oc * 50;
  float bv = bias[oc];
  const float* yb = ybuf + (size_t)b * 2 * NPIX;
  float m = -1e30f;
  #pragma unroll
  for (int dy = 0; dy < 2; ++dy)
    #pragma unroll
    for (int dx = 0; dx < 2; ++dx) {
      int i = 2 * py + dy, j = 2 * px + dx;
      float s = bv;
      #pragma unroll
      for (int ic = 0; ic < 2; ++ic)
        #pragma unroll
        for (int a = 0; a < 5; ++a)
          #pragma unroll
          for (int q = 0; q < 5; ++q)
            s += yb[ic * NPIX + (i + a) * HW + (j + q)] * W[ic * 25 + a * 5 + q];
      m = fmaxf(m, s);
    }
  d1[idx] = fmaxf(m, 0.f);
}

// ---------------- decoder conv2 (6->16, 5x5 valid) + relu + maxpool2 -> flat ----------------
__global__ __launch_bounds__(256) void dconv2_kernel(const float* __restrict__ d1,
                                                     const float* __restrict__ dp_w,
                                                     const float* __restrict__ dr_w,
                                                     const float* __restrict__ bias,
                                                     float* __restrict__ flat) {
  int idx = blockIdx.x * 256 + threadIdx.x;
  if (idx >= 2 * NB * 16 * 289) return;
  int d = idx / (NB * 16 * 289);
  int rem = idx % (NB * 16 * 289);
  int b = rem / (16 * 289);
  int rem2 = rem % (16 * 289);
  int oc = rem2 / 289, pp = rem2 % 289;
  int py = pp / 17, px = pp % 17;
  const float* W = (d ? dr_w : dp_w) + oc * 150;
  float bv = bias[oc];
  const float* in = d1 + ((size_t)d * NB + b) * 6 * 1444;
  float m = -1e30f;
  #pragma unroll
  for (int dy = 0; dy < 2; ++dy)
    #pragma unroll
    for (int dx = 0; dx < 2; ++dx) {
      int i = 2 * py + dy, j = 2 * px + dx;
      float s = bv;
      for (int ic = 0; ic < 6; ++ic)
        #pragma unroll
        for (int a = 0; a < 5; ++a)
          #pragma unroll
          for (int q = 0; q < 5; ++q)
            s += in[ic * 1444 + (i + a) * 38 + (j + q)] * W[ic * 25 + a * 5 + q];
      m = fmaxf(m, s);
    }
  flat[((size_t)d * NB + b) * NLIN + oc * 289 + pp] = fmaxf(m, 0.f);
}

// ---------------- linear layers: one wave per output row, float4 streaming ----------------
__global__ __launch_bounds__(256) void lin_kernel(const float* __restrict__ in,
                                                  const float* __restrict__ dp_w,
                                                  const float* __restrict__ dr_w,
                                                  const float* __restrict__ bias,
                                                  float* __restrict__ out,
                                                  int n_out) {
  int wid = blockIdx.x * 4 + (threadIdx.x >> 6);
  int lane = threadIdx.x & 63;
  if (wid >= 2 * n_out) return;
  int d = wid / n_out, o = wid % n_out;
  const float4* W = (const float4*)((d ? dr_w : dp_w) + (size_t)o * NLIN);
  const float4* F = (const float4*)(in + (size_t)d * NB * NLIN);
  float acc[NB];
  #pragma unroll
  for (int b = 0; b < NB; ++b) acc[b] = 0.f;
  for (int i = lane; i < NLIN / 4; i += 64) {
    float4 wv = W[i];
    #pragma unroll
    for (int b = 0; b < NB; ++b) {
      float4 xv = F[b * (NLIN / 4) + i];
      acc[b] += wv.x * xv.x + wv.y * xv.y + wv.z * xv.z + wv.w * xv.w;
    }
  }
  #pragma unroll
  for (int b = 0; b < NB; ++b)
    #pragma unroll
    for (int off = 32; off; off >>= 1) acc[b] += __shfl_down(acc[b], off);
  if (lane == 0) {
    float bv = bias[o];
    #pragma unroll
    for (int b = 0; b < NB; ++b)
      out[((size_t)d * NB + b) * n_out + o] = fmaxf(acc[b] + bv, 0.f);
  }
}

// ---------------- final 2312 -> 1 + sigmoid ----------------
__global__ __launch_bounds__(1024) void lin3_kernel(const float* __restrict__ in,
                                                    const float* __restrict__ dp_w,
                                                    const float* __restrict__ dr_w,
                                                    const float* __restrict__ bias,
                                                    float* __restrict__ out) {
  int wv = threadIdx.x >> 6;     // 16 waves: d*8 + b
  int lane = threadIdx.x & 63;
  int d = wv / NB, b = wv % NB;
  const float* W = d ? dr_w : dp_w;
  const float* x = in + (size_t)wv * NL2;
  float acc = 0.f;
  for (int i = lane; i < NL2; i += 64) acc += x[i] * W[i];
  #pragma unroll
  for (int off = 32; off; off >>= 1) acc += __shfl_down(acc, off);
  if (lane == 0) out[d * NB + b] = 1.f / (1.f + expf(-(acc + bias[0])));
}

extern "C" void kernel_launch(void* const* d_in, const int* in_sizes, int n_in,
                              void* d_out, int out_size, void* d_ws, size_t ws_size,
                              hipStream_t stream) {
  const float* x      = (const float*)d_in[0];
  const float* mc_w1  = (const float*)d_in[1];
  const float* mc_g1  = (const float*)d_in[2];
  const float* mc_b1  = (const float*)d_in[3];
  const float* mc_w2  = (const float*)d_in[4];
  const float* mc_g2  = (const float*)d_in[5];
  const float* mc_b2  = (const float*)d_in[6];
  const float* mc_wd  = (const float*)d_in[7];
  const float* mc_gd  = (const float*)d_in[8];
  const float* mc_bd  = (const float*)d_in[9];
  const float* ms_w1  = (const float*)d_in[10];
  const float* ms_g1  = (const float*)d_in[11];
  const float* ms_b1  = (const float*)d_in[12];
  const float* ms_w2  = (const float*)d_in[13];
  const float* ms_g2  = (const float*)d_in[14];
  const float* ms_b2  = (const float*)d_in[15];
  const float* ms_wd  = (const float*)d_in[16];
  const float* ms_gd  = (const float*)d_in[17];
  const float* ms_bd  = (const float*)d_in[18];
  const float* sf_w   = (const float*)d_in[19];
  const float* sf_b   = (const float*)d_in[20];
  const float* cf_cw_w= (const float*)d_in[21];
  const float* cf_cw_b= (const float*)d_in[22];
  const float* cf_dw  = (const float*)d_in[23];
  const float* cf_db  = (const float*)d_in[24];
  const float* dp_c1w = (const float*)d_in[25];
  const float* dp_c1b = (const float*)d_in[26];
  const float* dp_c2w = (const float*)d_in[27];
  const float* dp_c2b = (const float*)d_in[28];
  const float* dp_l1w = (const float*)d_in[29];
  const float* dp_l1b = (const float*)d_in[30];
  const float* dp_l2w = (const float*)d_in[31];
  const float* dp_l2b = (const float*)d_in[32];
  const float* dp_l3w = (const float*)d_in[33];
  const float* dp_l3b = (const float*)d_in[34];
  const float* dr_c1w = (const float*)d_in[35];
  const float* dr_c2w = (const float*)d_in[36];
  const float* dr_l1w = (const float*)d_in[37];
  const float* dr_l2w = (const float*)d_in[38];
  const float* dr_l3w = (const float*)d_in[39];

  float* ws = (float*)d_ws;
  float* x_enc    = ws;                       // 8*64*6400 = 3,276,800
  float* x1_enc   = x_enc    + 3276800;       // 8*6400
  float* spat_msb = x1_enc   + 51200;         // 8*6400
  float* P        = spat_msb + 51200;         // 8*64*25
  float* xs       = P        + 12800;         // 8*6400
  float* cfb      = xs       + 51200;         // 8*64*25
  float* ybuf     = cfb      + 12800;         // 8*2*6400
  float* d1       = ybuf     + 102400;        // 2*8*6*38*38 = 138,624
  float* flat     = d1       + 138624;        // 2*8*4624
  float* l1o      = flat     + 73984;         // 2*8*4624
  float* l2o      = l1o      + 73984;         // 2*8*2312

  encoder_kernel<<<520, 256, 0, stream>>>(x, x_enc, x1_enc);
  msb_kernel<<<520, 256, 0, stream>>>(x_enc, x1_enc,
      mc_w1, mc_g1, mc_b1, mc_w2, mc_g2, mc_b2, mc_wd, mc_gd, mc_bd,
      ms_w1, ms_g1, ms_b1, ms_w2, ms_g2, ms_b2, ms_wd, ms_gd, ms_bd,
      P, spat_msb);
  fsum_kernel<<<200, 256, 0, stream>>>(x_enc, xs);
  spat_kernel<<<200, 256, 0, stream>>>(spat_msb, xs, sf_w, sf_b, ybuf);
  cf_mix_kernel<<<200, 64, 0, stream>>>(P, cf_cw_w, cf_cw_b, cf_dw, cf_db, cfb);
  chan_conv_kernel<<<160, 320, 0, stream>>>(x_enc, cfb, ybuf);
  dconv1_kernel<<<542, 256, 0, stream>>>(ybuf, dp_c1w, dr_c1w, dp_c1b, d1);
  dconv2_kernel<<<289, 256, 0, stream>>>(d1, dp_c2w, dr_c2w, dp_c2b, flat);
  lin_kernel<<<2312, 256, 0, stream>>>(flat, dp_l1w, dr_l1w, dp_l1b, l1o, NLIN);
  lin_kernel<<<1156, 256, 0, stream>>>(l1o, dp_l2w, dr_l2w, dp_l2b, l2o, NL2);
  lin3_kernel<<<1, 1024, 0, stream>>>(l2o, dp_l3w, dr_l3w, dp_l3b, (float*)d_out);
}

// Round 7
// 818.956 us; speedup vs baseline: 1.3632x; 1.3632x over previous
//
#include <hip/hip_runtime.h>

#define HW 80
#define NPIX 6400
#define NF 64
#define NB 8
#define NLIN 4624
#define NL2 2312

// fast tanh via hardware v_exp_f32; clamp keeps exp finite, error ~1e-7
__device__ __forceinline__ float fast_tanh(float v) {
  v = fminf(fmaxf(v, -15.f), 15.f);
  float e = __expf(2.f * v);
  return __fdividef(e - 1.f, e + 1.f);
}

// ---------------- jax-style bilinear (triangle, antialias) taps — STATIC 3-tap form ----------------
// All loops compile-time unrolled; w[] stays in registers (no scratch). Out-of-window taps get w=0.
__device__ __forceinline__ void resize_taps3(int o, int n_in, int n_out, int* i0, float w[3]) {
  float inv = (float)n_in / (float)n_out;
  float ks = inv > 1.f ? inv : 1.f;          // antialias kernel scale = max(in/out, 1)
  float sf = ((float)o + 0.5f) * inv - 0.5f;
  int lo = (int)ceilf(sf - ks);
  if (lo < 0) lo = 0;
  int hi = (int)floorf(sf + ks);
  if (hi > n_in - 1) hi = n_in - 1;
  float tot = 0.f;
  #pragma unroll
  for (int k = 0; k < 3; ++k) {
    int pos = lo + k;
    float dd = fabsf((float)pos - sf) / ks;
    float ww = fmaxf(1.f - dd, 0.f);
    ww = (pos <= hi) ? ww : 0.f;
    w[k] = ww; tot += ww;
  }
  float r = 1.f / tot;
  #pragma unroll
  for (int k = 0; k < 3; ++k) w[k] *= r;
  *i0 = lo;
}

// ---------------- channel-max over f: x (8,64,80,80) -> x1raw (8,80,80), float4 ----------------
__global__ __launch_bounds__(256) void maxplane_kernel(const float* __restrict__ x,
                                                       float* __restrict__ x1raw) {
  int idx = blockIdx.x * 256 + threadIdx.x;     // 8 * 1600 float4
  if (idx >= NB * 1600) return;
  int b = idx / 1600, q = idx % 1600;
  const float4* pb = (const float4*)(x + (size_t)b * NF * NPIX);
  float4 m = pb[q];
  for (int f = 1; f < NF; ++f) {
    float4 v = pb[f * 1600 + q];
    m.x = fmaxf(m.x, v.x); m.y = fmaxf(m.y, v.y);
    m.z = fmaxf(m.z, v.z); m.w = fmaxf(m.w, v.w);
  }
  ((float4*)x1raw)[idx] = m;
}

// ---------------- encoder: 3x(avg3+tanh+max3) + resize 68->80, one WG per plane ----------------
// blocks 0..511: planes of x. blocks 512..519: precomputed x1raw planes. Uniform work per block.
__global__ __launch_bounds__(256) void encoder_kernel(const float* __restrict__ x,
                                                      const float* __restrict__ x1raw,
                                                      float* __restrict__ x_enc,
                                                      float* __restrict__ x1_enc) {
  __shared__ float b0[6400];
  __shared__ float b1[6084];
  int p = blockIdx.x, t = threadIdx.x;
  const float4* src4 = (const float4*)((p < 512) ? (x + (size_t)p * NPIX)
                                                 : (x1raw + (size_t)(p - 512) * NPIX));
  for (int i = t; i < 1600; i += 256) ((float4*)b0)[i] = src4[i];
  __syncthreads();
  int sz = 80;
  for (int L = 0; L < 3; ++L) {
    int s1 = sz - 2;
    for (int i = t; i < s1 * s1; i += 256) {
      int r = i / s1, c = i % s1;
      float s = 0.f;
      #pragma unroll
      for (int dr = 0; dr < 3; ++dr)
        #pragma unroll
        for (int dc = 0; dc < 3; ++dc) s += b0[(r + dr) * sz + (c + dc)];
      b1[i] = fast_tanh(s * (1.f / 9.f));
    }
    __syncthreads();
    int s2 = s1 - 2;
    for (int i = t; i < s2 * s2; i += 256) {
      int r = i / s2, c = i % s2;
      float m = -1e30f;
      #pragma unroll
      for (int dr = 0; dr < 3; ++dr)
        #pragma unroll
        for (int dc = 0; dc < 3; ++dc) m = fmaxf(m, b1[(r + dr) * s1 + (c + dc)]);
      b0[i] = m;
    }
    __syncthreads();
    sz = s2;
  }
  // sz == 68; bilinear resize 68 -> 80 (static 3-tap)
  float* dst = (p < 512) ? (x_enc + (size_t)p * NPIX) : (x1_enc + (size_t)(p - 512) * NPIX);
  for (int i = t; i < NPIX; i += 256) {
    int r = i / HW, c = i % HW;
    int r0, c0; float wr[3], wc[3];
    resize_taps3(r, 68, 80, &r0, wr);
    resize_taps3(c, 68, 80, &c0, wc);
    float v = 0.f;
    #pragma unroll
    for (int a = 0; a < 3; ++a) {
      int rr = r0 + a; rr = rr > 67 ? 67 : rr;
      float rv = 0.f;
      #pragma unroll
      for (int bq = 0; bq < 3; ++bq) {
        int cc = c0 + bq; cc = cc > 67 ? 67 : cc;
        rv += wc[bq] * b0[rr * 68 + cc];
      }
      v += wr[a] * rv;
    }
    dst[i] = v;
  }
}

// ---------------- MSB: per-plane conv2x2->81^2, conv4x4->79^2, bn+tanh, resize->80, 1x1 mix, bn.
__global__ __launch_bounds__(256) void msb_kernel(
    const float* __restrict__ x_enc, const float* __restrict__ x1_enc,
    const float* mc_w1, const float* mc_g1, const float* mc_b1,
    const float* mc_w2, const float* mc_g2, const float* mc_b2,
    const float* mc_wd, const float* mc_gd, const float* mc_bd,
    const float* ms_w1, const float* ms_g1, const float* ms_b1,
    const float* ms_w2, const float* ms_g2, const float* ms_b2,
    const float* ms_wd, const float* ms_gd, const float* ms_bd,
    float* __restrict__ P, float* __restrict__ spat_msb) {
  __shared__ float xin[6400];
  __shared__ float t1[6561];   // 81*81
  __shared__ float t2[6241];   // 79*79
  __shared__ float red[200];
  int p = blockIdx.x, t = threadIdx.x;
  bool chan_path = (p < 512);
  const float* src = chan_path ? (x_enc + (size_t)p * NPIX) : (x1_enc + (size_t)(p - 512) * NPIX);
  const float* w1p = chan_path ? mc_w1 : ms_w1;
  const float* w2p = chan_path ? mc_w2 : ms_w2;
  const float* wdp = chan_path ? mc_wd : ms_wd;
  const float rs = rsqrtf(1.f + 1e-5f);
  float s1 = (chan_path ? mc_g1[0] : ms_g1[0]) * rs;
  float o1 = (chan_path ? mc_b1[0] : ms_b1[0]);
  float s2 = (chan_path ? mc_g2[0] : ms_g2[0]) * rs;
  float o2 = (chan_path ? mc_b2[0] : ms_b2[0]);
  float sd = (chan_path ? mc_gd[0] : ms_gd[0]) * rs;
  float od = (chan_path ? mc_bd[0] : ms_bd[0]);
  float wd0 = wdp[0], wd1 = wdp[1];
  float W1[4], W2[16];
  #pragma unroll
  for (int k = 0; k < 4; ++k) W1[k] = w1p[k];
  #pragma unroll
  for (int k = 0; k < 16; ++k) W2[k] = w2p[k];

  const float4* src4 = (const float4*)src;
  for (int i = t; i < 1600; i += 256) ((float4*)xin)[i] = src4[i];
  __syncthreads();

  for (int i = t; i < 6561; i += 256) {
    int r = i / 81 - 1, c = i % 81 - 1;
    float s = 0.f;
    #pragma unroll
    for (int a = 0; a < 2; ++a) {
      int rr = r + a; if (rr < 0 || rr >= 80) continue;
      #pragma unroll
      for (int b = 0; b < 2; ++b) {
        int cc = c + b; if (cc < 0 || cc >= 80) continue;
        s += W1[a * 2 + b] * xin[rr * 80 + cc];
      }
    }
    t1[i] = fast_tanh(s * s1 + o1);
  }
  for (int i = t; i < 6241; i += 256) {
    int r = i / 79 - 1, c = i % 79 - 1;
    float s = 0.f;
    #pragma unroll
    for (int a = 0; a < 4; ++a) {
      int rr = r + a; if (rr < 0 || rr >= 80) continue;
      #pragma unroll
      for (int b = 0; b < 4; ++b) {
        int cc = c + b; if (cc < 0 || cc >= 80) continue;
        s += W2[a * 4 + b] * xin[rr * 80 + cc];
      }
    }
    t2[i] = fast_tanh(s * s2 + o2);
  }
  __syncthreads();

  // final 80x80: resize t1 (81->80) and t2 (79->80), mix, bn — static 3-tap, fully unrolled
  float vals[25];
  #pragma unroll
  for (int k = 0; k < 25; ++k) {
    int i = t + k * 256;
    int r = i / HW, c = i % HW;
    int r0, c0; float wr[3], wc[3];
    resize_taps3(r, 81, 80, &r0, wr);
    resize_taps3(c, 81, 80, &c0, wc);
    float v1 = 0.f;
    #pragma unroll
    for (int a = 0; a < 3; ++a) {
      int rr = r0 + a; rr = rr > 80 ? 80 : rr;
      float rv = 0.f;
      #pragma unroll
      for (int bq = 0; bq < 3; ++bq) {
        int cc = c0 + bq; cc = cc > 80 ? 80 : cc;
        rv += wc[bq] * t1[rr * 81 + cc];
      }
      v1 += wr[a] * rv;
    }
    resize_taps3(r, 79, 80, &r0, wr);
    resize_taps3(c, 79, 80, &c0, wc);
    float v2 = 0.f;
    #pragma unroll
    for (int a = 0; a < 3; ++a) {
      int rr = r0 + a; rr = rr > 78 ? 78 : rr;
      float rv = 0.f;
      #pragma unroll
      for (int bq = 0; bq < 3; ++bq) {
        int cc = c0 + bq; cc = cc > 78 ? 78 : cc;
        rv += wc[bq] * t2[rr * 79 + cc];
      }
      v2 += wr[a] * rv;
    }
    vals[k] = (v1 * wd0 + v2 * wd1) * sd + od;
  }
  if (chan_path) {
    #pragma unroll
    for (int k = 0; k < 25; ++k) xin[t + k * 256] = vals[k];
    __syncthreads();
    if (t < 200) {
      int bin = t >> 3, sub = t & 7;
      int ki = bin / 5, kj = bin % 5;
      int r0 = ki * 16 + sub * 2, c0 = kj * 16;
      float s = 0.f;
      for (int rr = r0; rr < r0 + 2; ++rr)
        for (int cc = c0; cc < c0 + 16; ++cc) s += xin[rr * 80 + cc];
      red[t] = s;
    }
    __syncthreads();
    if (t < 25) {
      float s = 0.f;
      #pragma unroll
      for (int k = 0; k < 8; ++k) s += red[t * 8 + k];
      P[(size_t)p * 25 + t] = s * (1.f / 256.f);
    }
  } else {
    float* dst = spat_msb + (size_t)(p - 512) * NPIX;
    #pragma unroll
    for (int k = 0; k < 25; ++k) dst[t + k * 256] = vals[k];
  }
}

// ---------------- xs = sum over f of x_enc, float4 ----------------
__global__ __launch_bounds__(256) void fsum_kernel(const float* __restrict__ x_enc, float* __restrict__ xs) {
  int idx = blockIdx.x * 256 + threadIdx.x;    // 8 * 1600 float4
  if (idx >= NB * 1600) return;
  int b = idx / 1600, q = idx % 1600;
  const float4* pb = (const float4*)(x_enc + (size_t)b * NF * NPIX);
  float4 s = pb[q];
  for (int f = 1; f < NF; ++f) {
    float4 v = pb[f * 1600 + q];
    s.x += v.x; s.y += v.y; s.z += v.z; s.w += v.w;
  }
  ((float4*)xs)[idx] = s;
}

// ---------------- spat_filter (25-softmax) fused with spat_o patch dot ----------------
__global__ __launch_bounds__(256) void spat_kernel(const float* __restrict__ spat_msb,
                                                   const float* __restrict__ xs,
                                                   const float* __restrict__ sf_w,
                                                   const float* __restrict__ sf_b,
                                                   float* __restrict__ ybuf /* (8,2,6400) */) {
  int idx = blockIdx.x * 256 + threadIdx.x;
  if (idx >= NB * NPIX) return;
  int b = idx / NPIX, pix = idx % NPIX;
  int h = pix / HW, w = pix % HW;
  float v = spat_msb[idx];
  float lg[25];
  float mx = -1e30f;
  #pragma unroll
  for (int c = 0; c < 25; ++c) {
    lg[c] = v * (sf_w[c] + 1.f) + sf_b[c];
    mx = fmaxf(mx, lg[c]);
  }
  float den = 0.f;
  #pragma unroll
  for (int c = 0; c < 25; ++c) { lg[c] = __expf(lg[c] - mx); den += lg[c]; }
  const float* xp = xs + (size_t)b * NPIX;
  float acc = 0.f;
  #pragma unroll
  for (int i = 0; i < 5; ++i) {
    int r = h + i - 2; if (r < 0 || r >= HW) continue;
    #pragma unroll
    for (int j = 0; j < 5; ++j) {
      int c2 = w + j - 2; if (c2 < 0 || c2 >= HW) continue;
      acc += lg[i * 5 + j] * xp[r * HW + c2];
    }
  }
  ybuf[(size_t)b * 2 * NPIX + pix] = acc / den;
}

// ---------------- chan_filter tail: P (8,64,25) -> cf (8,64,25) ----------------
__global__ __launch_bounds__(64) void cf_mix_kernel(const float* __restrict__ P,
                                                    const float* __restrict__ cw_w,
                                                    const float* __restrict__ cw_b,
                                                    const float* __restrict__ dw,
                                                    const float* __restrict__ db,
                                                    float* __restrict__ cf) {
  __shared__ float tmp[64];
  int blk = blockIdx.x;            // 200 = b*25 + bin
  int b = blk / 25, bin = blk % 25;
  int f = threadIdx.x;             // 64 = one wave
  float mw = 0.f, mb = 0.f;
  #pragma unroll
  for (int k = 0; k < 16; ++k) { mw += cw_w[k]; mb += cw_b[k]; }
  mw *= (1.f / 16.f); mb *= (1.f / 16.f);
  float pv = P[((size_t)b * 64 + f) * 25 + bin];
  float s = pv;
  #pragma unroll
  for (int off = 32; off; off >>= 1) s += __shfl_down(s, off);
  float Pm = __shfl(s, 0) * (1.f / 64.f);
  tmp[f] = pv * mw + mb + Pm;
  __syncthreads();
  const float* dwr = dw + f * 64;
  float acc = db[f];
  for (int k = 0; k < 64; ++k) acc += dwr[k] * tmp[k];
  cf[((size_t)b * 64 + f) * 25 + bin] = acc;
}

// ---------------- chan_o: per-batch per-channel 5x5 dynamic conv, summed over f ----------------
__global__ __launch_bounds__(320) void chan_conv_kernel(const float* __restrict__ x_enc,
                                                        const float* __restrict__ cf,
                                                        float* __restrict__ ybuf) {
  __shared__ float cfl[1600];
  int blk = blockIdx.x;          // 160 = b*20 + rowtile
  int b = blk / 20, rt = blk % 20;
  int t = threadIdx.x;           // 320 = 4 rows x 80
  for (int i = t; i < 1600; i += 320) cfl[i] = cf[(size_t)b * 1600 + i];
  __syncthreads();
  int r = rt * 4 + t / 80, c = t % 80;
  const float* xb = x_enc + (size_t)b * NF * NPIX;
  float acc = 0.f;
  for (int f = 0; f < NF; ++f) {
    const float* xp = xb + (size_t)f * NPIX;
    const float* cp = cfl + f * 25;
    #pragma unroll
    for (int i = 0; i < 5; ++i) {
      int rr = r + i - 2; if (rr < 0 || rr >= HW) continue;
      #pragma unroll
      for (int j = 0; j < 5; ++j) {
        int cc = c + j - 2; if (cc < 0 || cc >= HW) continue;
        acc += cp[i * 5 + j] * xp[rr * HW + cc];
      }
    }
  }
  ybuf[(size_t)b * 2 * NPIX + NPIX + r * HW + c] = acc;
}

// ---------------- decoder conv1 (2->6, 5x5 valid) + relu + maxpool2 ----------------
__global__ __launch_bounds__(256) void dconv1_kernel(const float* __restrict__ ybuf,
                                                     const float* __restrict__ dp_w,
                                                     const float* __restrict__ dr_w,
                                                     const float* __restrict__ bias,
                                                     float* __restrict__ d1) {
  int idx = blockIdx.x * 256 + threadIdx.x;
  if (idx >= 2 * NB * 6 * 38 * 38) return;
  int d = idx / (NB * 6 * 1444);
  int rem = idx % (NB * 6 * 1444);
  int b = rem / (6 * 1444);
  int rem2 = rem % (6 * 1444);
  int oc = rem2 / 1444, pp = rem2 % 1444;
  int py = pp / 38, px = pp % 38;
  const float* W = (d ? dr_w : dp_w) + oc * 50;
  float bv = bias[oc];
  const float* yb = ybuf + (size_t)b * 2 * NPIX;
  float m = -1e30f;
  #pragma unroll
  for (int dy = 0; dy < 2; ++dy)
    #pragma unroll
    for (int dx = 0; dx < 2; ++dx) {
      int i = 2 * py + dy, j = 2 * px + dx;
      float s = bv;
      #pragma unroll
      for (int ic = 0; ic < 2; ++ic)
        #pragma unroll
        for (int a = 0; a < 5; ++a)
          #pragma unroll
          for (int q = 0; q < 5; ++q)
            s += yb[ic * NPIX + (i + a) * HW + (j + q)] * W[ic * 25 + a * 5 + q];
      m = fmaxf(m, s);
    }
  d1[idx] = fmaxf(m, 0.f);
}

// ---------------- decoder conv2 (6->16, 5x5 valid) + relu + maxpool2 -> flat ----------------
__global__ __launch_bounds__(256) void dconv2_kernel(const float* __restrict__ d1,
                                                     const float* __restrict__ dp_w,
                                                     const float* __restrict__ dr_w,
                                                     const float* __restrict__ bias,
                                                     float* __restrict__ flat) {
  int idx = blockIdx.x * 256 + threadIdx.x;
  if (idx >= 2 * NB * 16 * 289) return;
  int d = idx / (NB * 16 * 289);
  int rem = idx % (NB * 16 * 289);
  int b = rem / (16 * 289);
  int rem2 = rem % (16 * 289);
  int oc = rem2 / 289, pp = rem2 % 289;
  int py = pp / 17, px = pp % 17;
  const float* W = (d ? dr_w : dp_w) + oc * 150;
  float bv = bias[oc];
  const float* in = d1 + ((size_t)d * NB + b) * 6 * 1444;
  float m = -1e30f;
  #pragma unroll
  for (int dy = 0; dy < 2; ++dy)
    #pragma unroll
    for (int dx = 0; dx < 2; ++dx) {
      int i = 2 * py + dy, j = 2 * px + dx;
      float s = bv;
      for (int ic = 0; ic < 6; ++ic)
        #pragma unroll
        for (int a = 0; a < 5; ++a)
          #pragma unroll
          for (int q = 0; q < 5; ++q)
            s += in[ic * 1444 + (i + a) * 38 + (j + q)] * W[ic * 25 + a * 5 + q];
      m = fmaxf(m, s);
    }
  flat[((size_t)d * NB + b) * NLIN + oc * 289 + pp] = fmaxf(m, 0.f);
}

// ---------------- linear layers: one wave per output row, float4 streaming ----------------
__global__ __launch_bounds__(256) void lin_kernel(const float* __restrict__ in,
                                                  const float* __restrict__ dp_w,
                                                  const float* __restrict__ dr_w,
                                                  const float* __restrict__ bias,
                                                  float* __restrict__ out,
                                                  int n_out) {
  int wid = blockIdx.x * 4 + (threadIdx.x >> 6);
  int lane = threadIdx.x & 63;
  if (wid >= 2 * n_out) return;
  int d = wid / n_out, o = wid % n_out;
  const float4* W = (const float4*)((d ? dr_w : dp_w) + (size_t)o * NLIN);
  const float4* F = (const float4*)(in + (size_t)d * NB * NLIN);
  float acc[NB];
  #pragma unroll
  for (int b = 0; b < NB; ++b) acc[b] = 0.f;
  for (int i = lane; i < NLIN / 4; i += 64) {
    float4 wv = W[i];
    #pragma unroll
    for (int b = 0; b < NB; ++b) {
      float4 xv = F[b * (NLIN / 4) + i];
      acc[b] += wv.x * xv.x + wv.y * xv.y + wv.z * xv.z + wv.w * xv.w;
    }
  }
  #pragma unroll
  for (int b = 0; b < NB; ++b)
    #pragma unroll
    for (int off = 32; off; off >>= 1) acc[b] += __shfl_down(acc[b], off);
  if (lane == 0) {
    float bv = bias[o];
    #pragma unroll
    for (int b = 0; b < NB; ++b)
      out[((size_t)d * NB + b) * n_out + o] = fmaxf(acc[b] + bv, 0.f);
  }
}

// ---------------- final 2312 -> 1 + sigmoid ----------------
__global__ __launch_bounds__(1024) void lin3_kernel(const float* __restrict__ in,
                                                    const float* __restrict__ dp_w,
                                                    const float* __restrict__ dr_w,
                                                    const float* __restrict__ bias,
                                                    float* __restrict__ out) {
  int wv = threadIdx.x >> 6;     // 16 waves: d*8 + b
  int lane = threadIdx.x & 63;
  int d = wv / NB, b = wv % NB;
  const float* W = d ? dr_w : dp_w;
  const float* x = in + (size_t)wv * NL2;
  float acc = 0.f;
  for (int i = lane; i < NL2; i += 64) acc += x[i] * W[i];
  #pragma unroll
  for (int off = 32; off; off >>= 1) acc += __shfl_down(acc, off);
  if (lane == 0) out[d * NB + b] = 1.f / (1.f + __expf(-(acc + bias[0])));
}

extern "C" void kernel_launch(void* const* d_in, const int* in_sizes, int n_in,
                              void* d_out, int out_size, void* d_ws, size_t ws_size,
                              hipStream_t stream) {
  const float* x      = (const float*)d_in[0];
  const float* mc_w1  = (const float*)d_in[1];
  const float* mc_g1  = (const float*)d_in[2];
  const float* mc_b1  = (const float*)d_in[3];
  const float* mc_w2  = (const float*)d_in[4];
  const float* mc_g2  = (const float*)d_in[5];
  const float* mc_b2  = (const float*)d_in[6];
  const float* mc_wd  = (const float*)d_in[7];
  const float* mc_gd  = (const float*)d_in[8];
  const float* mc_bd  = (const float*)d_in[9];
  const float* ms_w1  = (const float*)d_in[10];
  const float* ms_g1  = (const float*)d_in[11];
  const float* ms_b1  = (const float*)d_in[12];
  const float* ms_w2  = (const float*)d_in[13];
  const float* ms_g2  = (const float*)d_in[14];
  const float* ms_b2  = (const float*)d_in[15];
  const float* ms_wd  = (const float*)d_in[16];
  const float* ms_gd  = (const float*)d_in[17];
  const float* ms_bd  = (const float*)d_in[18];
  const float* sf_w   = (const float*)d_in[19];
  const float* sf_b   = (const float*)d_in[20];
  const float* cf_cw_w= (const float*)d_in[21];
  const float* cf_cw_b= (const float*)d_in[22];
  const float* cf_dw  = (const float*)d_in[23];
  const float* cf_db  = (const float*)d_in[24];
  const float* dp_c1w = (const float*)d_in[25];
  const float* dp_c1b = (const float*)d_in[26];
  const float* dp_c2w = (const float*)d_in[27];
  const float* dp_c2b = (const float*)d_in[28];
  const float* dp_l1w = (const float*)d_in[29];
  const float* dp_l1b = (const float*)d_in[30];
  const float* dp_l2w = (const float*)d_in[31];
  const float* dp_l2b = (const float*)d_in[32];
  const float* dp_l3w = (const float*)d_in[33];
  const float* dp_l3b = (const float*)d_in[34];
  const float* dr_c1w = (const float*)d_in[35];
  const float* dr_c2w = (const float*)d_in[36];
  const float* dr_l1w = (const float*)d_in[37];
  const float* dr_l2w = (const float*)d_in[38];
  const float* dr_l3w = (const float*)d_in[39];

  float* ws = (float*)d_ws;
  float* x_enc    = ws;                       // 8*64*6400 = 3,276,800
  float* x1raw    = x_enc    + 3276800;       // 8*6400
  float* x1_enc   = x1raw    + 51200;         // 8*6400
  float* spat_msb = x1_enc   + 51200;         // 8*6400
  float* P        = spat_msb + 51200;         // 8*64*25
  float* xs       = P        + 12800;         // 8*6400
  float* cfb      = xs       + 51200;         // 8*64*25
  float* ybuf     = cfb      + 12800;         // 8*2*6400
  float* d1       = ybuf     + 102400;        // 2*8*6*38*38 = 138,624
  float* flat     = d1       + 138624;        // 2*8*4624
  float* l1o      = flat     + 73984;         // 2*8*4624
  float* l2o      = l1o      + 73984;         // 2*8*2312

  maxplane_kernel<<<50, 256, 0, stream>>>(x, x1raw);
  encoder_kernel<<<520, 256, 0, stream>>>(x, x1raw, x_enc, x1_enc);
  msb_kernel<<<520, 256, 0, stream>>>(x_enc, x1_enc,
      mc_w1, mc_g1, mc_b1, mc_w2, mc_g2, mc_b2, mc_wd, mc_gd, mc_bd,
      ms_w1, ms_g1, ms_b1, ms_w2, ms_g2, ms_b2, ms_wd, ms_gd, ms_bd,
      P, spat_msb);
  fsum_kernel<<<50, 256, 0, stream>>>(x_enc, xs);
  spat_kernel<<<200, 256, 0, stream>>>(spat_msb, xs, sf_w, sf_b, ybuf);
  cf_mix_kernel<<<200, 64, 0, stream>>>(P, cf_cw_w, cf_cw_b, cf_dw, cf_db, cfb);
  chan_conv_kernel<<<160, 320, 0, stream>>>(x_enc, cfb, ybuf);
  dconv1_kernel<<<542, 256, 0, stream>>>(ybuf, dp_c1w, dr_c1w, dp_c1b, d1);
  dconv2_kernel<<<289, 256, 0, stream>>>(d1, dp_c2w, dr_c2w, dp_c2b, flat);
  lin_kernel<<<2312, 256, 0, stream>>>(flat, dp_l1w, dr_l1w, dp_l1b, l1o, NLIN);
  lin_kernel<<<1156, 256, 0, stream>>>(l1o, dp_l2w, dr_l2w, dp_l2b, l2o, NL2);
  lin3_kernel<<<1, 1024, 0, stream>>>(l2o, dp_l3w, dr_l3w, dp_l3b, (float*)d_out);
}

// Round 10
// 625.479 us; speedup vs baseline: 1.7849x; 1.3093x over previous
//
#include <hip/hip_runtime.h>

#define HW 80
#define NPIX 6400
#define NF 64
#define NB 8
#define NLIN 4624
#define NL2 2312

// fast tanh via hardware v_exp_f32; clamp keeps exp finite, error ~1e-7
__device__ __forceinline__ float fast_tanh(float v) {
  v = fminf(fmaxf(v, -15.f), 15.f);
  float e = __expf(2.f * v);
  return __fdividef(e - 1.f, e + 1.f);
}

// ---------------- jax-style bilinear (triangle, antialias) taps — STATIC 3-tap form ----------------
__device__ __forceinline__ void resize_taps3(int o, int n_in, int n_out, int* i0, float w[3]) {
  float inv = (float)n_in / (float)n_out;
  float ks = inv > 1.f ? inv : 1.f;
  float sf = ((float)o + 0.5f) * inv - 0.5f;
  int lo = (int)ceilf(sf - ks);
  if (lo < 0) lo = 0;
  int hi = (int)floorf(sf + ks);
  if (hi > n_in - 1) hi = n_in - 1;
  float tot = 0.f;
  #pragma unroll
  for (int k = 0; k < 3; ++k) {
    int pos = lo + k;
    float dd = fabsf((float)pos - sf) / ks;
    float ww = fmaxf(1.f - dd, 0.f);
    ww = (pos <= hi) ? ww : 0.f;
    w[k] = ww; tot += ww;
  }
  float r = 1.f / tot;
  #pragma unroll
  for (int k = 0; k < 3; ++k) w[k] *= r;
  *i0 = lo;
}

// ---------------- channel-max over f: x (8,64,80,80) -> x1raw (8,80,80), float4 ----------------
__global__ __launch_bounds__(256) void maxplane_kernel(const float* __restrict__ x,
                                                       float* __restrict__ x1raw) {
  int idx = blockIdx.x * 256 + threadIdx.x;     // 8 * 1600 float4
  if (idx >= NB * 1600) return;
  int b = idx / 1600, q = idx % 1600;
  const float4* pb = (const float4*)(x + (size_t)b * NF * NPIX);
  float4 m = pb[q];
  for (int f = 1; f < NF; ++f) {
    float4 v = pb[f * 1600 + q];
    m.x = fmaxf(m.x, v.x); m.y = fmaxf(m.y, v.y);
    m.z = fmaxf(m.z, v.z); m.w = fmaxf(m.w, v.w);
  }
  ((float4*)x1raw)[idx] = m;
}

// ---------------- encoder: 3x(avg3+tanh+max3) + resize 68->80, one WG per plane ----------------
__global__ __launch_bounds__(256) void encoder_kernel(const float* __restrict__ x,
                                                      const float* __restrict__ x1raw,
                                                      float* __restrict__ x_enc,
                                                      float* __restrict__ x1_enc) {
  __shared__ float b0[6400];
  __shared__ float b1[6084];
  int p = blockIdx.x, t = threadIdx.x;
  const float4* src4 = (const float4*)((p < 512) ? (x + (size_t)p * NPIX)
                                                 : (x1raw + (size_t)(p - 512) * NPIX));
  for (int i = t; i < 1600; i += 256) ((float4*)b0)[i] = src4[i];
  __syncthreads();
  int sz = 80;
  for (int L = 0; L < 3; ++L) {
    int s1 = sz - 2;
    for (int i = t; i < s1 * s1; i += 256) {
      int r = i / s1, c = i % s1;
      float s = 0.f;
      #pragma unroll
      for (int dr = 0; dr < 3; ++dr)
        #pragma unroll
        for (int dc = 0; dc < 3; ++dc) s += b0[(r + dr) * sz + (c + dc)];
      b1[i] = fast_tanh(s * (1.f / 9.f));
    }
    __syncthreads();
    int s2 = s1 - 2;
    for (int i = t; i < s2 * s2; i += 256) {
      int r = i / s2, c = i % s2;
      float m = -1e30f;
      #pragma unroll
      for (int dr = 0; dr < 3; ++dr)
        #pragma unroll
        for (int dc = 0; dc < 3; ++dc) m = fmaxf(m, b1[(r + dr) * s1 + (c + dc)]);
      b0[i] = m;
    }
    __syncthreads();
    sz = s2;
  }
  float* dst = (p < 512) ? (x_enc + (size_t)p * NPIX) : (x1_enc + (size_t)(p - 512) * NPIX);
  for (int i = t; i < NPIX; i += 256) {
    int r = i / HW, c = i % HW;
    int r0, c0; float wr[3], wc[3];
    resize_taps3(r, 68, 80, &r0, wr);
    resize_taps3(c, 68, 80, &c0, wc);
    float v = 0.f;
    #pragma unroll
    for (int a = 0; a < 3; ++a) {
      int rr = r0 + a; rr = rr > 67 ? 67 : rr;
      float rv = 0.f;
      #pragma unroll
      for (int bq = 0; bq < 3; ++bq) {
        int cc = c0 + bq; cc = cc > 67 ? 67 : cc;
        rv += wc[bq] * b0[rr * 68 + cc];
      }
      v += wr[a] * rv;
    }
    dst[i] = v;
  }
}

// ---------------- MSB: per-plane conv2x2->81^2, conv4x4->79^2, bn+tanh, resize->80, 1x1 mix, bn.
__global__ __launch_bounds__(256) void msb_kernel(
    const float* __restrict__ x_enc, const float* __restrict__ x1_enc,
    const float* mc_w1, const float* mc_g1, const float* mc_b1,
    const float* mc_w2, const float* mc_g2, const float* mc_b2,
    const float* mc_wd, const float* mc_gd, const float* mc_bd,
    const float* ms_w1, const float* ms_g1, const float* ms_b1,
    const float* ms_w2, const float* ms_g2, const float* ms_b2,
    const float* ms_wd, const float* ms_gd, const float* ms_bd,
    float* __restrict__ P, float* __restrict__ spat_msb) {
  __shared__ float xin[6400];
  __shared__ float t1[6561];   // 81*81
  __shared__ float t2[6241];   // 79*79
  __shared__ float red[200];
  int p = blockIdx.x, t = threadIdx.x;
  bool chan_path = (p < 512);
  const float* src = chan_path ? (x_enc + (size_t)p * NPIX) : (x1_enc + (size_t)(p - 512) * NPIX);
  const float* w1p = chan_path ? mc_w1 : ms_w1;
  const float* w2p = chan_path ? mc_w2 : ms_w2;
  const float* wdp = chan_path ? mc_wd : ms_wd;
  const float rs = rsqrtf(1.f + 1e-5f);
  float s1 = (chan_path ? mc_g1[0] : ms_g1[0]) * rs;
  float o1 = (chan_path ? mc_b1[0] : ms_b1[0]);
  float s2 = (chan_path ? mc_g2[0] : ms_g2[0]) * rs;
  float o2 = (chan_path ? mc_b2[0] : ms_b2[0]);
  float sd = (chan_path ? mc_gd[0] : ms_gd[0]) * rs;
  float od = (chan_path ? mc_bd[0] : ms_bd[0]);
  float wd0 = wdp[0], wd1 = wdp[1];
  float W1[4], W2[16];
  #pragma unroll
  for (int k = 0; k < 4; ++k) W1[k] = w1p[k];
  #pragma unroll
  for (int k = 0; k < 16; ++k) W2[k] = w2p[k];

  const float4* src4 = (const float4*)src;
  for (int i = t; i < 1600; i += 256) ((float4*)xin)[i] = src4[i];
  __syncthreads();

  for (int i = t; i < 6561; i += 256) {
    int r = i / 81 - 1, c = i % 81 - 1;
    float s = 0.f;
    #pragma unroll
    for (int a = 0; a < 2; ++a) {
      int rr = r + a; if (rr < 0 || rr >= 80) continue;
      #pragma unroll
      for (int b = 0; b < 2; ++b) {
        int cc = c + b; if (cc < 0 || cc >= 80) continue;
        s += W1[a * 2 + b] * xin[rr * 80 + cc];
      }
    }
    t1[i] = fast_tanh(s * s1 + o1);
  }
  for (int i = t; i < 6241; i += 256) {
    int r = i / 79 - 1, c = i % 79 - 1;
    float s = 0.f;
    #pragma unroll
    for (int a = 0; a < 4; ++a) {
      int rr = r + a; if (rr < 0 || rr >= 80) continue;
      #pragma unroll
      for (int b = 0; b < 4; ++b) {
        int cc = c + b; if (cc < 0 || cc >= 80) continue;
        s += W2[a * 4 + b] * xin[rr * 80 + cc];
      }
    }
    t2[i] = fast_tanh(s * s2 + o2);
  }
  __syncthreads();

  float vals[25];
  #pragma unroll
  for (int k = 0; k < 25; ++k) {
    int i = t + k * 256;
    int r = i / HW, c = i % HW;
    int r0, c0; float wr[3], wc[3];
    resize_taps3(r, 81, 80, &r0, wr);
    resize_taps3(c, 81, 80, &c0, wc);
    float v1 = 0.f;
    #pragma unroll
    for (int a = 0; a < 3; ++a) {
      int rr = r0 + a; rr = rr > 80 ? 80 : rr;
      float rv = 0.f;
      #pragma unroll
      for (int bq = 0; bq < 3; ++bq) {
        int cc = c0 + bq; cc = cc > 80 ? 80 : cc;
        rv += wc[bq] * t1[rr * 81 + cc];
      }
      v1 += wr[a] * rv;
    }
    resize_taps3(r, 79, 80, &r0, wr);
    resize_taps3(c, 79, 80, &c0, wc);
    float v2 = 0.f;
    #pragma unroll
    for (int a = 0; a < 3; ++a) {
      int rr = r0 + a; rr = rr > 78 ? 78 : rr;
      float rv = 0.f;
      #pragma unroll
      for (int bq = 0; bq < 3; ++bq) {
        int cc = c0 + bq; cc = cc > 78 ? 78 : cc;
        rv += wc[bq] * t2[rr * 79 + cc];
      }
      v2 += wr[a] * rv;
    }
    vals[k] = (v1 * wd0 + v2 * wd1) * sd + od;
  }
  if (chan_path) {
    #pragma unroll
    for (int k = 0; k < 25; ++k) xin[t + k * 256] = vals[k];
    __syncthreads();
    if (t < 200) {
      int bin = t >> 3, sub = t & 7;
      int ki = bin / 5, kj = bin % 5;
      int r0 = ki * 16 + sub * 2, c0 = kj * 16;
      float s = 0.f;
      for (int rr = r0; rr < r0 + 2; ++rr)
        for (int cc = c0; cc < c0 + 16; ++cc) s += xin[rr * 80 + cc];
      red[t] = s;
    }
    __syncthreads();
    if (t < 25) {
      float s = 0.f;
      #pragma unroll
      for (int k = 0; k < 8; ++k) s += red[t * 8 + k];
      P[(size_t)p * 25 + t] = s * (1.f / 256.f);
    }
  } else {
    float* dst = spat_msb + (size_t)(p - 512) * NPIX;
    #pragma unroll
    for (int k = 0; k < 25; ++k) dst[t + k * 256] = vals[k];
  }
}

// ---------------- xs = sum over f of x_enc, float4 ----------------
__global__ __launch_bounds__(256) void fsum_kernel(const float* __restrict__ x_enc, float* __restrict__ xs) {
  int idx = blockIdx.x * 256 + threadIdx.x;    // 8 * 1600 float4
  if (idx >= NB * 1600) return;
  int b = idx / 1600, q = idx % 1600;
  const float4* pb = (const float4*)(x_enc + (size_t)b * NF * NPIX);
  float4 s = pb[q];
  for (int f = 1; f < NF; ++f) {
    float4 v = pb[f * 1600 + q];
    s.x += v.x; s.y += v.y; s.z += v.z; s.w += v.w;
  }
  ((float4*)xs)[idx] = s;
}

// ---------------- spat_filter (25-softmax) fused with spat_o patch dot ----------------
__global__ __launch_bounds__(256) void spat_kernel(const float* __restrict__ spat_msb,
                                                   const float* __restrict__ xs,
                                                   const float* __restrict__ sf_w,
                                                   const float* __restrict__ sf_b,
                                                   float* __restrict__ ybuf /* (8,2,6400) */) {
  int idx = blockIdx.x * 256 + threadIdx.x;
  if (idx >= NB * NPIX) return;
  int b = idx / NPIX, pix = idx % NPIX;
  int h = pix / HW, w = pix % HW;
  float v = spat_msb[idx];
  float lg[25];
  float mx = -1e30f;
  #pragma unroll
  for (int c = 0; c < 25; ++c) {
    lg[c] = v * (sf_w[c] + 1.f) + sf_b[c];
    mx = fmaxf(mx, lg[c]);
  }
  float den = 0.f;
  #pragma unroll
  for (int c = 0; c < 25; ++c) { lg[c] = __expf(lg[c] - mx); den += lg[c]; }
  const float* xp = xs + (size_t)b * NPIX;
  float acc = 0.f;
  #pragma unroll
  for (int i = 0; i < 5; ++i) {
    int r = h + i - 2; if (r < 0 || r >= HW) continue;
    #pragma unroll
    for (int j = 0; j < 5; ++j) {
      int c2 = w + j - 2; if (c2 < 0 || c2 >= HW) continue;
      acc += lg[i * 5 + j] * xp[r * HW + c2];
    }
  }
  ybuf[(size_t)b * 2 * NPIX + pix] = acc / den;
}

// ---------------- chan_filter tail: P (8,64,25) -> cf (8,64,25) ----------------
__global__ __launch_bounds__(64) void cf_mix_kernel(const float* __restrict__ P,
                                                    const float* __restrict__ cw_w,
                                                    const float* __restrict__ cw_b,
                                                    const float* __restrict__ dw,
                                                    const float* __restrict__ db,
                                                    float* __restrict__ cf) {
  __shared__ float tmp[64];
  int blk = blockIdx.x;            // 200 = b*25 + bin
  int b = blk / 25, bin = blk % 25;
  int f = threadIdx.x;             // 64 = one wave
  float mw = 0.f, mb = 0.f;
  #pragma unroll
  for (int k = 0; k < 16; ++k) { mw += cw_w[k]; mb += cw_b[k]; }
  mw *= (1.f / 16.f); mb *= (1.f / 16.f);
  float pv = P[((size_t)b * 64 + f) * 25 + bin];
  float s = pv;
  #pragma unroll
  for (int off = 32; off; off >>= 1) s += __shfl_down(s, off);
  float Pm = __shfl(s, 0) * (1.f / 64.f);
  tmp[f] = pv * mw + mb + Pm;
  __syncthreads();
  const float* dwr = dw + f * 64;
  float acc = db[f];
  for (int k = 0; k < 64; ++k) acc += dwr[k] * tmp[k];
  cf[((size_t)b * 64 + f) * 25 + bin] = acc;
}

// ---------------- chan_o stage A: 16-f partial sums, LDS-staged rows ----------------
// grid: 640 = ((b*4)+fg)*20 + rt. 320 threads = 4 output rows x 80 cols.
__global__ __launch_bounds__(320) void chan_partial_kernel(const float* __restrict__ x_enc,
                                                           const float* __restrict__ cf,
                                                           float* __restrict__ partial) {
  __shared__ float xsh[16][8][80];   // 16 f x 8 halo rows x 80 cols = 40 KB
  __shared__ float cfl[400];         // 16 f x 25 taps
  int blk = blockIdx.x;
  int rt = blk % 20, fg = (blk / 20) % 4, b = blk / 80;
  int t = threadIdx.x;
  int r0 = rt * 4;                   // output rows r0..r0+3; input rows r0-2..r0+5
  for (int q = t; q < 2560; q += 320) {        // 2560 float4 = 16f x 8rows x 20
    int lf = q / 160, rem = q % 160;
    int lr = rem / 20, c4 = rem % 20;
    int row = r0 - 2 + lr;
    float4 v = make_float4(0.f, 0.f, 0.f, 0.f);
    if (row >= 0 && row < 80)
      v = *(const float4*)(x_enc + (size_t)(b * NF + fg * 16 + lf) * NPIX + row * 80 + c4 * 4);
    *(float4*)(&xsh[lf][lr][c4 * 4]) = v;
  }
  for (int q = t; q < 400; q += 320)           // FIX: 400 entries, 320 threads -> strided loop
    cfl[q] = cf[(size_t)b * 1600 + fg * 400 + q];
  __syncthreads();
  int lr = t / 80, c = t % 80;
  float acc = 0.f;
  for (int lf = 0; lf < 16; ++lf) {
    const float* cp = cfl + lf * 25;
    #pragma unroll
    for (int i = 0; i < 5; ++i) {
      #pragma unroll
      for (int j = 0; j < 5; ++j) {
        int cc = c + j - 2;
        float xv = (cc >= 0 && cc < 80) ? xsh[lf][lr + i][cc] : 0.f;
        acc += cp[i * 5 + j] * xv;
      }
    }
  }
  partial[(size_t)fg * 51200 + b * 6400 + (r0 + lr) * 80 + c] = acc;
}

// ---------------- chan_o stage B: sum 4 partials -> ybuf chan half ----------------
__global__ __launch_bounds__(256) void chan_reduce_kernel(const float* __restrict__ partial,
                                                          float* __restrict__ ybuf) {
  int idx = blockIdx.x * 256 + threadIdx.x;
  if (idx >= NB * NPIX) return;
  int b = idx / NPIX, pix = idx % NPIX;
  float s = partial[idx] + partial[51200 + idx] + partial[102400 + idx] + partial[153600 + idx];
  ybuf[(size_t)b * 2 * NPIX + NPIX + pix] = s;
}

// ---------------- decoder conv1 (2->6, 5x5 valid) + relu + maxpool2, LDS-staged ----------------
// grid 96 = (d*8+b)*6 + oc; 256 threads.
__global__ __launch_bounds__(256) void dconv1_kernel(const float* __restrict__ ybuf,
                                                     const float* __restrict__ dp_w,
                                                     const float* __restrict__ dr_w,
                                                     const float* __restrict__ bias,
                                                     float* __restrict__ d1) {
  __shared__ float yin[2 * 6400];    // 51.2 KB
  __shared__ float Wl[50];
  int blk = blockIdx.x;
  int oc = blk % 6, b = (blk / 6) % 8, d = blk / 48;
  int t = threadIdx.x;
  const float4* src4 = (const float4*)(ybuf + (size_t)b * 2 * NPIX);
  for (int q = t; q < 3200; q += 256) ((float4*)yin)[q] = src4[q];
  if (t < 50) Wl[t] = (d ? dr_w : dp_w)[oc * 50 + t];
  __syncthreads();
  float bv = bias[oc];
  for (int pp = t; pp < 1444; pp += 256) {
    int py = pp / 38, px = pp % 38;
    float m = -1e30f;
    #pragma unroll
    for (int dy = 0; dy < 2; ++dy)
      #pragma unroll
      for (int dx = 0; dx < 2; ++dx) {
        int i = 2 * py + dy, j = 2 * px + dx;
        float s = bv;
        #pragma unroll
        for (int ic = 0; ic < 2; ++ic)
          #pragma unroll
          for (int a = 0; a < 5; ++a)
            #pragma unroll
            for (int q = 0; q < 5; ++q)
              s += yin[ic * NPIX + (i + a) * HW + (j + q)] * Wl[ic * 25 + a * 5 + q];
        m = fmaxf(m, s);
      }
    d1[((size_t)(d * NB + b) * 6 + oc) * 1444 + pp] = fmaxf(m, 0.f);
  }
}

// ---------------- decoder conv2 (6->16, 5x5 valid) + relu + maxpool2 -> flat, LDS-staged ----------------
// grid 256 = (d*8+b)*16 + oc; 320 threads (one output each, 289 active).
__global__ __launch_bounds__(320) void dconv2_kernel(const float* __restrict__ d1,
                                                     const float* __restrict__ dp_w,
                                                     const float* __restrict__ dr_w,
                                                     const float* __restrict__ bias,
                                                     float* __restrict__ flat) {
  __shared__ float din[6 * 1444];    // 34.7 KB
  __shared__ float Wl[150];
  int blk = blockIdx.x;
  int oc = blk % 16, b = (blk / 16) % 8, d = blk / 128;
  int t = threadIdx.x;
  const float4* src4 = (const float4*)(d1 + (size_t)(d * NB + b) * 6 * 1444);
  for (int q = t; q < 2166; q += 320) ((float4*)din)[q] = src4[q];
  if (t < 150) Wl[t] = (d ? dr_w : dp_w)[oc * 150 + t];
  __syncthreads();
  if (t >= 289) return;
  int py = t / 17, px = t % 17;
  float bv = bias[oc];
  float m = -1e30f;
  #pragma unroll
  for (int dy = 0; dy < 2; ++dy)
    #pragma unroll
    for (int dx = 0; dx < 2; ++dx) {
      int i = 2 * py + dy, j = 2 * px + dx;
      float s = bv;
      for (int ic = 0; ic < 6; ++ic)
        #pragma unroll
        for (int a = 0; a < 5; ++a)
          #pragma unroll
          for (int q = 0; q < 5; ++q)
            s += din[ic * 1444 + (i + a) * 38 + (j + q)] * Wl[ic * 25 + a * 5 + q];
      m = fmaxf(m, s);
    }
  flat[((size_t)d * NB + b) * NLIN + oc * 289 + t] = fmaxf(m, 0.f);
}

// ---------------- linear layers: one wave per output row, float4 streaming ----------------
__global__ __launch_bounds__(256) void lin_kernel(const float* __restrict__ in,
                                                  const float* __restrict__ dp_w,
                                                  const float* __restrict__ dr_w,
                                                  const float* __restrict__ bias,
                                                  float* __restrict__ out,
                                                  int n_out) {
  int wid = blockIdx.x * 4 + (threadIdx.x >> 6);
  int lane = threadIdx.x & 63;
  if (wid >= 2 * n_out) return;
  int d = wid / n_out, o = wid % n_out;
  const float4* W = (const float4*)((d ? dr_w : dp_w) + (size_t)o * NLIN);
  const float4* F = (const float4*)(in + (size_t)d * NB * NLIN);
  float acc[NB];
  #pragma unroll
  for (int b = 0; b < NB; ++b) acc[b] = 0.f;
  for (int i = lane; i < NLIN / 4; i += 64) {
    float4 wv = W[i];
    #pragma unroll
    for (int b = 0; b < NB; ++b) {
      float4 xv = F[b * (NLIN / 4) + i];
      acc[b] += wv.x * xv.x + wv.y * xv.y + wv.z * xv.z + wv.w * xv.w;
    }
  }
  #pragma unroll
  for (int b = 0; b < NB; ++b)
    #pragma unroll
    for (int off = 32; off; off >>= 1) acc[b] += __shfl_down(acc[b], off);
  if (lane == 0) {
    float bv = bias[o];
    #pragma unroll
    for (int b = 0; b < NB; ++b)
      out[((size_t)d * NB + b) * n_out + o] = fmaxf(acc[b] + bv, 0.f);
  }
}

// ---------------- final 2312 -> 1 + sigmoid ----------------
__global__ __launch_bounds__(1024) void lin3_kernel(const float* __restrict__ in,
                                                    const float* __restrict__ dp_w,
                                                    const float* __restrict__ dr_w,
                                                    const float* __restrict__ bias,
                                                    float* __restrict__ out) {
  int wv = threadIdx.x >> 6;     // 16 waves: d*8 + b
  int lane = threadIdx.x & 63;
  int d = wv / NB, b = wv % NB;
  const float* W = d ? dr_w : dp_w;
  const float* x = in + (size_t)wv * NL2;
  float acc = 0.f;
  for (int i = lane; i < NL2; i += 64) acc += x[i] * W[i];
  #pragma unroll
  for (int off = 32; off; off >>= 1) acc += __shfl_down(acc, off);
  if (lane == 0) out[d * NB + b] = 1.f / (1.f + __expf(-(acc + bias[0])));
}

extern "C" void kernel_launch(void* const* d_in, const int* in_sizes, int n_in,
                              void* d_out, int out_size, void* d_ws, size_t ws_size,
                              hipStream_t stream) {
  const float* x      = (const float*)d_in[0];
  const float* mc_w1  = (const float*)d_in[1];
  const float* mc_g1  = (const float*)d_in[2];
  const float* mc_b1  = (const float*)d_in[3];
  const float* mc_w2  = (const float*)d_in[4];
  const float* mc_g2  = (const float*)d_in[5];
  const float* mc_b2  = (const float*)d_in[6];
  const float* mc_wd  = (const float*)d_in[7];
  const float* mc_gd  = (const float*)d_in[8];
  const float* mc_bd  = (const float*)d_in[9];
  const float* ms_w1  = (const float*)d_in[10];
  const float* ms_g1  = (const float*)d_in[11];
  const float* ms_b1  = (const float*)d_in[12];
  const float* ms_w2  = (const float*)d_in[13];
  const float* ms_g2  = (const float*)d_in[14];
  const float* ms_b2  = (const float*)d_in[15];
  const float* ms_wd  = (const float*)d_in[16];
  const float* ms_gd  = (const float*)d_in[17];
  const float* ms_bd  = (const float*)d_in[18];
  const float* sf_w   = (const float*)d_in[19];
  const float* sf_b   = (const float*)d_in[20];
  const float* cf_cw_w= (const float*)d_in[21];
  const float* cf_cw_b= (const float*)d_in[22];
  const float* cf_dw  = (const float*)d_in[23];
  const float* cf_db  = (const float*)d_in[24];
  const float* dp_c1w = (const float*)d_in[25];
  const float* dp_c1b = (const float*)d_in[26];
  const float* dp_c2w = (const float*)d_in[27];
  const float* dp_c2b = (const float*)d_in[28];
  const float* dp_l1w = (const float*)d_in[29];
  const float* dp_l1b = (const float*)d_in[30];
  const float* dp_l2w = (const float*)d_in[31];
  const float* dp_l2b = (const float*)d_in[32];
  const float* dp_l3w = (const float*)d_in[33];
  const float* dp_l3b = (const float*)d_in[34];
  const float* dr_c1w = (const float*)d_in[35];
  const float* dr_c2w = (const float*)d_in[36];
  const float* dr_l1w = (const float*)d_in[37];
  const float* dr_l2w = (const float*)d_in[38];
  const float* dr_l3w = (const float*)d_in[39];

  float* ws = (float*)d_ws;
  float* x_enc    = ws;                       // 8*64*6400 = 3,276,800
  float* x1raw    = x_enc    + 3276800;       // 8*6400
  float* x1_enc   = x1raw    + 51200;         // 8*6400
  float* spat_msb = x1_enc   + 51200;         // 8*6400
  float* P        = spat_msb + 51200;         // 8*64*25
  float* xs       = P        + 12800;         // 8*6400
  float* cfb      = xs       + 51200;         // 8*64*25
  float* ybuf     = cfb      + 12800;         // 8*2*6400
  float* d1       = ybuf     + 102400;        // 2*8*6*38*38 = 138,624
  float* flat     = d1       + 138624;        // 2*8*4624
  float* l1o      = flat     + 73984;         // 2*8*4624
  float* l2o      = l1o      + 73984;         // 2*8*2312
  // chan partials (4*51200 = 204,800 floats) alias the d1.. region: consumed by
  // chan_reduce BEFORE dconv1 writes d1 (stream-ordered, no overlap in time).
  float* partial  = d1;

  maxplane_kernel<<<50, 256, 0, stream>>>(x, x1raw);
  encoder_kernel<<<520, 256, 0, stream>>>(x, x1raw, x_enc, x1_enc);
  msb_kernel<<<520, 256, 0, stream>>>(x_enc, x1_enc,
      mc_w1, mc_g1, mc_b1, mc_w2, mc_g2, mc_b2, mc_wd, mc_gd, mc_bd,
      ms_w1, ms_g1, ms_b1, ms_w2, ms_g2, ms_b2, ms_wd, ms_gd, ms_bd,
      P, spat_msb);
  fsum_kernel<<<50, 256, 0, stream>>>(x_enc, xs);
  spat_kernel<<<200, 256, 0, stream>>>(spat_msb, xs, sf_w, sf_b, ybuf);
  cf_mix_kernel<<<200, 64, 0, stream>>>(P, cf_cw_w, cf_cw_b, cf_dw, cf_db, cfb);
  chan_partial_kernel<<<640, 320, 0, stream>>>(x_enc, cfb, partial);
  chan_reduce_kernel<<<200, 256, 0, stream>>>(partial, ybuf);
  dconv1_kernel<<<96, 256, 0, stream>>>(ybuf, dp_c1w, dr_c1w, dp_c1b, d1);
  dconv2_kernel<<<256, 320, 0, stream>>>(d1, dp_c2w, dr_c2w, dp_c2b, flat);
  lin_kernel<<<2312, 256, 0, stream>>>(flat, dp_l1w, dr_l1w, dp_l1b, l1o, NLIN);
  lin_kernel<<<1156, 256, 0, stream>>>(l1o, dp_l2w, dr_l2w, dp_l2b, l2o, NL2);
  lin3_kernel<<<1, 1024, 0, stream>>>(l2o, dp_l3w, dr_l3w, dp_l3b, (float*)d_out);
}

// Round 11
// 589.694 us; speedup vs baseline: 1.8932x; 1.0607x over previous
//
#include <hip/hip_runtime.h>

#define HW 80
#define NPIX 6400
#define NF 64
#define NB 8
#define NLIN 4624
#define NL2 2312

// fast tanh via hardware v_exp_f32; clamp keeps exp finite, error ~1e-7
__device__ __forceinline__ float fast_tanh(float v) {
  v = fminf(fmaxf(v, -15.f), 15.f);
  float e = __expf(2.f * v);
  return __fdividef(e - 1.f, e + 1.f);
}

// ---------------- jax-style bilinear (triangle, antialias) taps — STATIC 3-tap form ----------------
__device__ __forceinline__ void resize_taps3(int o, int n_in, int n_out, int* i0, float w[3]) {
  float inv = (float)n_in / (float)n_out;
  float ks = inv > 1.f ? inv : 1.f;
  float sf = ((float)o + 0.5f) * inv - 0.5f;
  int lo = (int)ceilf(sf - ks);
  if (lo < 0) lo = 0;
  int hi = (int)floorf(sf + ks);
  if (hi > n_in - 1) hi = n_in - 1;
  float tot = 0.f;
  #pragma unroll
  for (int k = 0; k < 3; ++k) {
    int pos = lo + k;
    float dd = fabsf((float)pos - sf) / ks;
    float ww = fmaxf(1.f - dd, 0.f);
    ww = (pos <= hi) ? ww : 0.f;
    w[k] = ww; tot += ww;
  }
  float r = 1.f / tot;
  #pragma unroll
  for (int k = 0; k < 3; ++k) w[k] *= r;
  *i0 = lo;
}

// ---------------- channel-max over f: x (8,64,80,80) -> x1raw (8,80,80), float4 ----------------
__global__ __launch_bounds__(256) void maxplane_kernel(const float* __restrict__ x,
                                                       float* __restrict__ x1raw) {
  int idx = blockIdx.x * 256 + threadIdx.x;     // 8 * 1600 float4
  if (idx >= NB * 1600) return;
  int b = idx / 1600, q = idx % 1600;
  const float4* pb = (const float4*)(x + (size_t)b * NF * NPIX);
  float4 m = pb[q];
  for (int f = 1; f < NF; ++f) {
    float4 v = pb[f * 1600 + q];
    m.x = fmaxf(m.x, v.x); m.y = fmaxf(m.y, v.y);
    m.z = fmaxf(m.z, v.z); m.w = fmaxf(m.w, v.w);
  }
  ((float4*)x1raw)[idx] = m;
}

// ---------------- encoder: 3x(avg3+tanh+max3) + resize 68->80, one WG per plane ----------------
__global__ __launch_bounds__(256) void encoder_kernel(const float* __restrict__ x,
                                                      const float* __restrict__ x1raw,
                                                      float* __restrict__ x_enc,
                                                      float* __restrict__ x1_enc) {
  __shared__ float b0[6400];
  __shared__ float b1[6084];
  int p = blockIdx.x, t = threadIdx.x;
  const float4* src4 = (const float4*)((p < 512) ? (x + (size_t)p * NPIX)
                                                 : (x1raw + (size_t)(p - 512) * NPIX));
  for (int i = t; i < 1600; i += 256) ((float4*)b0)[i] = src4[i];
  __syncthreads();
  int sz = 80;
  for (int L = 0; L < 3; ++L) {
    int s1 = sz - 2;
    for (int i = t; i < s1 * s1; i += 256) {
      int r = i / s1, c = i % s1;
      float s = 0.f;
      #pragma unroll
      for (int dr = 0; dr < 3; ++dr)
        #pragma unroll
        for (int dc = 0; dc < 3; ++dc) s += b0[(r + dr) * sz + (c + dc)];
      b1[i] = fast_tanh(s * (1.f / 9.f));
    }
    __syncthreads();
    int s2 = s1 - 2;
    for (int i = t; i < s2 * s2; i += 256) {
      int r = i / s2, c = i % s2;
      float m = -1e30f;
      #pragma unroll
      for (int dr = 0; dr < 3; ++dr)
        #pragma unroll
        for (int dc = 0; dc < 3; ++dc) m = fmaxf(m, b1[(r + dr) * s1 + (c + dc)]);
      b0[i] = m;
    }
    __syncthreads();
    sz = s2;
  }
  float* dst = (p < 512) ? (x_enc + (size_t)p * NPIX) : (x1_enc + (size_t)(p - 512) * NPIX);
  for (int i = t; i < NPIX; i += 256) {
    int r = i / HW, c = i % HW;
    int r0, c0; float wr[3], wc[3];
    resize_taps3(r, 68, 80, &r0, wr);
    resize_taps3(c, 68, 80, &c0, wc);
    float v = 0.f;
    #pragma unroll
    for (int a = 0; a < 3; ++a) {
      int rr = r0 + a; rr = rr > 67 ? 67 : rr;
      float rv = 0.f;
      #pragma unroll
      for (int bq = 0; bq < 3; ++bq) {
        int cc = c0 + bq; cc = cc > 67 ? 67 : cc;
        rv += wc[bq] * b0[rr * 68 + cc];
      }
      v += wr[a] * rv;
    }
    dst[i] = v;
  }
}

// ---------------- MSB: per-plane conv2x2->81^2, conv4x4->79^2, bn+tanh, resize->80, 1x1 mix, bn.
__global__ __launch_bounds__(256) void msb_kernel(
    const float* __restrict__ x_enc, const float* __restrict__ x1_enc,
    const float* mc_w1, const float* mc_g1, const float* mc_b1,
    const float* mc_w2, const float* mc_g2, const float* mc_b2,
    const float* mc_wd, const float* mc_gd, const float* mc_bd,
    const float* ms_w1, const float* ms_g1, const float* ms_b1,
    const float* ms_w2, const float* ms_g2, const float* ms_b2,
    const float* ms_wd, const float* ms_gd, const float* ms_bd,
    float* __restrict__ P, float* __restrict__ spat_msb) {
  __shared__ float xin[6400];
  __shared__ float t1[6561];   // 81*81
  __shared__ float t2[6241];   // 79*79
  __shared__ float red[200];
  int p = blockIdx.x, t = threadIdx.x;
  bool chan_path = (p < 512);
  const float* src = chan_path ? (x_enc + (size_t)p * NPIX) : (x1_enc + (size_t)(p - 512) * NPIX);
  const float* w1p = chan_path ? mc_w1 : ms_w1;
  const float* w2p = chan_path ? mc_w2 : ms_w2;
  const float* wdp = chan_path ? mc_wd : ms_wd;
  const float rs = rsqrtf(1.f + 1e-5f);
  float s1 = (chan_path ? mc_g1[0] : ms_g1[0]) * rs;
  float o1 = (chan_path ? mc_b1[0] : ms_b1[0]);
  float s2 = (chan_path ? mc_g2[0] : ms_g2[0]) * rs;
  float o2 = (chan_path ? mc_b2[0] : ms_b2[0]);
  float sd = (chan_path ? mc_gd[0] : ms_gd[0]) * rs;
  float od = (chan_path ? mc_bd[0] : ms_bd[0]);
  float wd0 = wdp[0], wd1 = wdp[1];
  float W1[4], W2[16];
  #pragma unroll
  for (int k = 0; k < 4; ++k) W1[k] = w1p[k];
  #pragma unroll
  for (int k = 0; k < 16; ++k) W2[k] = w2p[k];

  const float4* src4 = (const float4*)src;
  for (int i = t; i < 1600; i += 256) ((float4*)xin)[i] = src4[i];
  __syncthreads();

  for (int i = t; i < 6561; i += 256) {
    int r = i / 81 - 1, c = i % 81 - 1;
    float s = 0.f;
    #pragma unroll
    for (int a = 0; a < 2; ++a) {
      int rr = r + a; if (rr < 0 || rr >= 80) continue;
      #pragma unroll
      for (int b = 0; b < 2; ++b) {
        int cc = c + b; if (cc < 0 || cc >= 80) continue;
        s += W1[a * 2 + b] * xin[rr * 80 + cc];
      }
    }
    t1[i] = fast_tanh(s * s1 + o1);
  }
  for (int i = t; i < 6241; i += 256) {
    int r = i / 79 - 1, c = i % 79 - 1;
    float s = 0.f;
    #pragma unroll
    for (int a = 0; a < 4; ++a) {
      int rr = r + a; if (rr < 0 || rr >= 80) continue;
      #pragma unroll
      for (int b = 0; b < 4; ++b) {
        int cc = c + b; if (cc < 0 || cc >= 80) continue;
        s += W2[a * 4 + b] * xin[rr * 80 + cc];
      }
    }
    t2[i] = fast_tanh(s * s2 + o2);
  }
  __syncthreads();

  float vals[25];
  #pragma unroll
  for (int k = 0; k < 25; ++k) {
    int i = t + k * 256;
    int r = i / HW, c = i % HW;
    int r0, c0; float wr[3], wc[3];
    resize_taps3(r, 81, 80, &r0, wr);
    resize_taps3(c, 81, 80, &c0, wc);
    float v1 = 0.f;
    #pragma unroll
    for (int a = 0; a < 3; ++a) {
      int rr = r0 + a; rr = rr > 80 ? 80 : rr;
      float rv = 0.f;
      #pragma unroll
      for (int bq = 0; bq < 3; ++bq) {
        int cc = c0 + bq; cc = cc > 80 ? 80 : cc;
        rv += wc[bq] * t1[rr * 81 + cc];
      }
      v1 += wr[a] * rv;
    }
    resize_taps3(r, 79, 80, &r0, wr);
    resize_taps3(c, 79, 80, &c0, wc);
    float v2 = 0.f;
    #pragma unroll
    for (int a = 0; a < 3; ++a) {
      int rr = r0 + a; rr = rr > 78 ? 78 : rr;
      float rv = 0.f;
      #pragma unroll
      for (int bq = 0; bq < 3; ++bq) {
        int cc = c0 + bq; cc = cc > 78 ? 78 : cc;
        rv += wc[bq] * t2[rr * 79 + cc];
      }
      v2 += wr[a] * rv;
    }
    vals[k] = (v1 * wd0 + v2 * wd1) * sd + od;
  }
  if (chan_path) {
    #pragma unroll
    for (int k = 0; k < 25; ++k) xin[t + k * 256] = vals[k];
    __syncthreads();
    if (t < 200) {
      int bin = t >> 3, sub = t & 7;
      int ki = bin / 5, kj = bin % 5;
      int r0 = ki * 16 + sub * 2, c0 = kj * 16;
      float s = 0.f;
      for (int rr = r0; rr < r0 + 2; ++rr)
        for (int cc = c0; cc < c0 + 16; ++cc) s += xin[rr * 80 + cc];
      red[t] = s;
    }
    __syncthreads();
    if (t < 25) {
      float s = 0.f;
      #pragma unroll
      for (int k = 0; k < 8; ++k) s += red[t * 8 + k];
      P[(size_t)p * 25 + t] = s * (1.f / 256.f);
    }
  } else {
    float* dst = spat_msb + (size_t)(p - 512) * NPIX;
    #pragma unroll
    for (int k = 0; k < 25; ++k) dst[t + k * 256] = vals[k];
  }
}

// ---------------- xs = sum over f of x_enc, float4 ----------------
__global__ __launch_bounds__(256) void fsum_kernel(const float* __restrict__ x_enc, float* __restrict__ xs) {
  int idx = blockIdx.x * 256 + threadIdx.x;    // 8 * 1600 float4
  if (idx >= NB * 1600) return;
  int b = idx / 1600, q = idx % 1600;
  const float4* pb = (const float4*)(x_enc + (size_t)b * NF * NPIX);
  float4 s = pb[q];
  for (int f = 1; f < NF; ++f) {
    float4 v = pb[f * 1600 + q];
    s.x += v.x; s.y += v.y; s.z += v.z; s.w += v.w;
  }
  ((float4*)xs)[idx] = s;
}

// ---------------- spat_filter (25-softmax) fused with spat_o patch dot ----------------
__global__ __launch_bounds__(256) void spat_kernel(const float* __restrict__ spat_msb,
                                                   const float* __restrict__ xs,
                                                   const float* __restrict__ sf_w,
                                                   const float* __restrict__ sf_b,
                                                   float* __restrict__ ybuf /* (8,2,6400) */) {
  int idx = blockIdx.x * 256 + threadIdx.x;
  if (idx >= NB * NPIX) return;
  int b = idx / NPIX, pix = idx % NPIX;
  int h = pix / HW, w = pix % HW;
  float v = spat_msb[idx];
  float lg[25];
  float mx = -1e30f;
  #pragma unroll
  for (int c = 0; c < 25; ++c) {
    lg[c] = v * (sf_w[c] + 1.f) + sf_b[c];
    mx = fmaxf(mx, lg[c]);
  }
  float den = 0.f;
  #pragma unroll
  for (int c = 0; c < 25; ++c) { lg[c] = __expf(lg[c] - mx); den += lg[c]; }
  const float* xp = xs + (size_t)b * NPIX;
  float acc = 0.f;
  #pragma unroll
  for (int i = 0; i < 5; ++i) {
    int r = h + i - 2; if (r < 0 || r >= HW) continue;
    #pragma unroll
    for (int j = 0; j < 5; ++j) {
      int c2 = w + j - 2; if (c2 < 0 || c2 >= HW) continue;
      acc += lg[i * 5 + j] * xp[r * HW + c2];
    }
  }
  ybuf[(size_t)b * 2 * NPIX + pix] = acc / den;
}

// ---------------- chan_filter tail: P (8,64,25) -> cf (8,64,25) ----------------
__global__ __launch_bounds__(64) void cf_mix_kernel(const float* __restrict__ P,
                                                    const float* __restrict__ cw_w,
                                                    const float* __restrict__ cw_b,
                                                    const float* __restrict__ dw,
                                                    const float* __restrict__ db,
                                                    float* __restrict__ cf) {
  __shared__ float tmp[64];
  int blk = blockIdx.x;            // 200 = b*25 + bin
  int b = blk / 25, bin = blk % 25;
  int f = threadIdx.x;             // 64 = one wave
  float mw = 0.f, mb = 0.f;
  #pragma unroll
  for (int k = 0; k < 16; ++k) { mw += cw_w[k]; mb += cw_b[k]; }
  mw *= (1.f / 16.f); mb *= (1.f / 16.f);
  float pv = P[((size_t)b * 64 + f) * 25 + bin];
  float s = pv;
  #pragma unroll
  for (int off = 32; off; off >>= 1) s += __shfl_down(s, off);
  float Pm = __shfl(s, 0) * (1.f / 64.f);
  tmp[f] = pv * mw + mb + Pm;
  __syncthreads();
  const float* dwr = dw + f * 64;
  float acc = db[f];
  for (int k = 0; k < 64; ++k) acc += dwr[k] * tmp[k];
  cf[((size_t)b * 64 + f) * 25 + bin] = acc;
}

// ---------------- chan_o stage A: 16-f partial sums, LDS-staged rows ----------------
// grid: 640 = ((b*4)+fg)*20 + rt. 320 threads = 4 output rows x 80 cols.
__global__ __launch_bounds__(320) void chan_partial_kernel(const float* __restrict__ x_enc,
                                                           const float* __restrict__ cf,
                                                           float* __restrict__ partial) {
  __shared__ float xsh[16][8][80];   // 16 f x 8 halo rows x 80 cols = 40 KB
  __shared__ float cfl[400];         // 16 f x 25 taps
  int blk = blockIdx.x;
  int rt = blk % 20, fg = (blk / 20) % 4, b = blk / 80;
  int t = threadIdx.x;
  int r0 = rt * 4;                   // output rows r0..r0+3; input rows r0-2..r0+5
  for (int q = t; q < 2560; q += 320) {        // 2560 float4 = 16f x 8rows x 20
    int lf = q / 160, rem = q % 160;
    int lr = rem / 20, c4 = rem % 20;
    int row = r0 - 2 + lr;
    float4 v = make_float4(0.f, 0.f, 0.f, 0.f);
    if (row >= 0 && row < 80)
      v = *(const float4*)(x_enc + (size_t)(b * NF + fg * 16 + lf) * NPIX + row * 80 + c4 * 4);
    *(float4*)(&xsh[lf][lr][c4 * 4]) = v;
  }
  for (int q = t; q < 400; q += 320)           // 400 entries, 320 threads -> strided loop
    cfl[q] = cf[(size_t)b * 1600 + fg * 400 + q];
  __syncthreads();
  int lr = t / 80, c = t % 80;
  float acc = 0.f;
  for (int lf = 0; lf < 16; ++lf) {
    const float* cp = cfl + lf * 25;
    #pragma unroll
    for (int i = 0; i < 5; ++i) {
      #pragma unroll
      for (int j = 0; j < 5; ++j) {
        int cc = c + j - 2;
        float xv = (cc >= 0 && cc < 80) ? xsh[lf][lr + i][cc] : 0.f;
        acc += cp[i * 5 + j] * xv;
      }
    }
  }
  partial[(size_t)fg * 51200 + b * 6400 + (r0 + lr) * 80 + c] = acc;
}

// ---------------- chan_o stage B: sum 4 partials -> ybuf chan half ----------------
__global__ __launch_bounds__(256) void chan_reduce_kernel(const float* __restrict__ partial,
                                                          float* __restrict__ ybuf) {
  int idx = blockIdx.x * 256 + threadIdx.x;
  if (idx >= NB * NPIX) return;
  int b = idx / NPIX, pix = idx % NPIX;
  float s = partial[idx] + partial[51200 + idx] + partial[102400 + idx] + partial[153600 + idx];
  ybuf[(size_t)b * 2 * NPIX + NPIX + pix] = s;
}

// ---------------- decoder conv1 (2->6, 5x5 valid) + relu + maxpool2, LDS-staged ----------------
// grid 96 = (d*8+b)*6 + oc; 256 threads.
__global__ __launch_bounds__(256) void dconv1_kernel(const float* __restrict__ ybuf,
                                                     const float* __restrict__ dp_w,
                                                     const float* __restrict__ dr_w,
                                                     const float* __restrict__ bias,
                                                     float* __restrict__ d1) {
  __shared__ float yin[2 * 6400];    // 51.2 KB
  __shared__ float Wl[50];
  int blk = blockIdx.x;
  int oc = blk % 6, b = (blk / 6) % 8, d = blk / 48;
  int t = threadIdx.x;
  const float4* src4 = (const float4*)(ybuf + (size_t)b * 2 * NPIX);
  for (int q = t; q < 3200; q += 256) ((float4*)yin)[q] = src4[q];
  if (t < 50) Wl[t] = (d ? dr_w : dp_w)[oc * 50 + t];
  __syncthreads();
  float bv = bias[oc];
  for (int pp = t; pp < 1444; pp += 256) {
    int py = pp / 38, px = pp % 38;
    float m = -1e30f;
    #pragma unroll
    for (int dy = 0; dy < 2; ++dy)
      #pragma unroll
      for (int dx = 0; dx < 2; ++dx) {
        int i = 2 * py + dy, j = 2 * px + dx;
        float s = bv;
        #pragma unroll
        for (int ic = 0; ic < 2; ++ic)
          #pragma unroll
          for (int a = 0; a < 5; ++a)
            #pragma unroll
            for (int q = 0; q < 5; ++q)
              s += yin[ic * NPIX + (i + a) * HW + (j + q)] * Wl[ic * 25 + a * 5 + q];
        m = fmaxf(m, s);
      }
    d1[((size_t)(d * NB + b) * 6 + oc) * 1444 + pp] = fmaxf(m, 0.f);
  }
}

// ---------------- decoder conv2 (6->16, 5x5 valid) + relu + maxpool2 -> flat, LDS-staged ----------------
// grid 256 = (d*8+b)*16 + oc; 320 threads (one output each, 289 active).
__global__ __launch_bounds__(320) void dconv2_kernel(const float* __restrict__ d1,
                                                     const float* __restrict__ dp_w,
                                                     const float* __restrict__ dr_w,
                                                     const float* __restrict__ bias,
                                                     float* __restrict__ flat) {
  __shared__ float din[6 * 1444];    // 34.7 KB
  __shared__ float Wl[150];
  int blk = blockIdx.x;
  int oc = blk % 16, b = (blk / 16) % 8, d = blk / 128;
  int t = threadIdx.x;
  const float4* src4 = (const float4*)(d1 + (size_t)(d * NB + b) * 6 * 1444);
  for (int q = t; q < 2166; q += 320) ((float4*)din)[q] = src4[q];
  if (t < 150) Wl[t] = (d ? dr_w : dp_w)[oc * 150 + t];
  __syncthreads();
  if (t >= 289) return;
  int py = t / 17, px = t % 17;
  float bv = bias[oc];
  float m = -1e30f;
  #pragma unroll
  for (int dy = 0; dy < 2; ++dy)
    #pragma unroll
    for (int dx = 0; dx < 2; ++dx) {
      int i = 2 * py + dy, j = 2 * px + dx;
      float s = bv;
      for (int ic = 0; ic < 6; ++ic)
        #pragma unroll
        for (int a = 0; a < 5; ++a)
          #pragma unroll
          for (int q = 0; q < 5; ++q)
            s += din[ic * 1444 + (i + a) * 38 + (j + q)] * Wl[ic * 25 + a * 5 + q];
      m = fmaxf(m, s);
    }
  flat[((size_t)d * NB + b) * NLIN + oc * 289 + t] = fmaxf(m, 0.f);
}

// ---------------- linear layers: 4 rows per wave, clustered loads for MLP ----------------
// grid = 2*n_out/16 blocks (4 waves/block, 4 rows/wave). n_out % 4 == 0 keeps d uniform per wave.
__global__ __launch_bounds__(256, 2) void lin_kernel(const float* __restrict__ in,
                                                     const float* __restrict__ dp_w,
                                                     const float* __restrict__ dr_w,
                                                     const float* __restrict__ bias,
                                                     float* __restrict__ out,
                                                     int n_out) {
  int wid = blockIdx.x * 4 + (threadIdx.x >> 6);
  int lane = threadIdx.x & 63;
  int row0 = wid * 4;
  if (row0 >= 2 * n_out) return;
  int d = row0 / n_out, o0 = row0 % n_out;
  const float* Wb = (d ? dr_w : dp_w) + (size_t)o0 * NLIN;
  const float4* W0 = (const float4*)(Wb);
  const float4* W1 = (const float4*)(Wb + NLIN);
  const float4* W2 = (const float4*)(Wb + 2 * NLIN);
  const float4* W3 = (const float4*)(Wb + 3 * NLIN);
  const float4* F = (const float4*)(in + (size_t)d * NB * NLIN);
  float acc[4][NB];
  #pragma unroll
  for (int r = 0; r < 4; ++r)
    #pragma unroll
    for (int b = 0; b < NB; ++b) acc[r][b] = 0.f;
  for (int i = lane; i < NLIN / 4; i += 64) {
    float4 w0 = W0[i], w1 = W1[i], w2 = W2[i], w3 = W3[i];
    float4 fv[NB];
    #pragma unroll
    for (int b = 0; b < NB; ++b) fv[b] = F[b * (NLIN / 4) + i];
    #pragma unroll
    for (int b = 0; b < NB; ++b) {
      acc[0][b] += w0.x * fv[b].x + w0.y * fv[b].y + w0.z * fv[b].z + w0.w * fv[b].w;
      acc[1][b] += w1.x * fv[b].x + w1.y * fv[b].y + w1.z * fv[b].z + w1.w * fv[b].w;
      acc[2][b] += w2.x * fv[b].x + w2.y * fv[b].y + w2.z * fv[b].z + w2.w * fv[b].w;
      acc[3][b] += w3.x * fv[b].x + w3.y * fv[b].y + w3.z * fv[b].z + w3.w * fv[b].w;
    }
  }
  #pragma unroll
  for (int r = 0; r < 4; ++r) {
    #pragma unroll
    for (int b = 0; b < NB; ++b) {
      float v = acc[r][b];
      #pragma unroll
      for (int off = 32; off; off >>= 1) v += __shfl_down(v, off);
      if (lane == 0)
        out[((size_t)d * NB + b) * n_out + o0 + r] = fmaxf(v + bias[o0 + r], 0.f);
    }
  }
}

// ---------------- final 2312 -> 1 + sigmoid ----------------
__global__ __launch_bounds__(1024) void lin3_kernel(const float* __restrict__ in,
                                                    const float* __restrict__ dp_w,
                                                    const float* __restrict__ dr_w,
                                                    const float* __restrict__ bias,
                                                    float* __restrict__ out) {
  int wv = threadIdx.x >> 6;     // 16 waves: d*8 + b
  int lane = threadIdx.x & 63;
  int d = wv / NB, b = wv % NB;
  const float* W = d ? dr_w : dp_w;
  const float* x = in + (size_t)wv * NL2;
  float acc = 0.f;
  for (int i = lane; i < NL2; i += 64) acc += x[i] * W[i];
  #pragma unroll
  for (int off = 32; off; off >>= 1) acc += __shfl_down(acc, off);
  if (lane == 0) out[d * NB + b] = 1.f / (1.f + __expf(-(acc + bias[0])));
}

extern "C" void kernel_launch(void* const* d_in, const int* in_sizes, int n_in,
                              void* d_out, int out_size, void* d_ws, size_t ws_size,
                              hipStream_t stream) {
  const float* x      = (const float*)d_in[0];
  const float* mc_w1  = (const float*)d_in[1];
  const float* mc_g1  = (const float*)d_in[2];
  const float* mc_b1  = (const float*)d_in[3];
  const float* mc_w2  = (const float*)d_in[4];
  const float* mc_g2  = (const float*)d_in[5];
  const float* mc_b2  = (const float*)d_in[6];
  const float* mc_wd  = (const float*)d_in[7];
  const float* mc_gd  = (const float*)d_in[8];
  const float* mc_bd  = (const float*)d_in[9];
  const float* ms_w1  = (const float*)d_in[10];
  const float* ms_g1  = (const float*)d_in[11];
  const float* ms_b1  = (const float*)d_in[12];
  const float* ms_w2  = (const float*)d_in[13];
  const float* ms_g2  = (const float*)d_in[14];
  const float* ms_b2  = (const float*)d_in[15];
  const float* ms_wd  = (const float*)d_in[16];
  const float* ms_gd  = (const float*)d_in[17];
  const float* ms_bd  = (const float*)d_in[18];
  const float* sf_w   = (const float*)d_in[19];
  const float* sf_b   = (const float*)d_in[20];
  const float* cf_cw_w= (const float*)d_in[21];
  const float* cf_cw_b= (const float*)d_in[22];
  const float* cf_dw  = (const float*)d_in[23];
  const float* cf_db  = (const float*)d_in[24];
  const float* dp_c1w = (const float*)d_in[25];
  const float* dp_c1b = (const float*)d_in[26];
  const float* dp_c2w = (const float*)d_in[27];
  const float* dp_c2b = (const float*)d_in[28];
  const float* dp_l1w = (const float*)d_in[29];
  const float* dp_l1b = (const float*)d_in[30];
  const float* dp_l2w = (const float*)d_in[31];
  const float* dp_l2b = (const float*)d_in[32];
  const float* dp_l3w = (const float*)d_in[33];
  const float* dp_l3b = (const float*)d_in[34];
  const float* dr_c1w = (const float*)d_in[35];
  const float* dr_c2w = (const float*)d_in[36];
  const float* dr_l1w = (const float*)d_in[37];
  const float* dr_l2w = (const float*)d_in[38];
  const float* dr_l3w = (const float*)d_in[39];

  float* ws = (float*)d_ws;
  float* x_enc    = ws;                       // 8*64*6400 = 3,276,800
  float* x1raw    = x_enc    + 3276800;       // 8*6400
  float* x1_enc   = x1raw    + 51200;         // 8*6400
  float* spat_msb = x1_enc   + 51200;         // 8*6400
  float* P        = spat_msb + 51200;         // 8*64*25
  float* xs       = P        + 12800;         // 8*6400
  float* cfb      = xs       + 51200;         // 8*64*25
  float* ybuf     = cfb      + 12800;         // 8*2*6400
  float* d1       = ybuf     + 102400;        // 2*8*6*38*38 = 138,624
  float* flat     = d1       + 138624;        // 2*8*4624
  float* l1o      = flat     + 73984;         // 2*8*4624
  float* l2o      = l1o      + 73984;         // 2*8*2312
  // chan partials (4*51200 = 204,800 floats) alias the d1.. region: consumed by
  // chan_reduce BEFORE dconv1 writes d1 (stream-ordered, no overlap in time).
  float* partial  = d1;

  maxplane_kernel<<<50, 256, 0, stream>>>(x, x1raw);
  encoder_kernel<<<520, 256, 0, stream>>>(x, x1raw, x_enc, x1_enc);
  msb_kernel<<<520, 256, 0, stream>>>(x_enc, x1_enc,
      mc_w1, mc_g1, mc_b1, mc_w2, mc_g2, mc_b2, mc_wd, mc_gd, mc_bd,
      ms_w1, ms_g1, ms_b1, ms_w2, ms_g2, ms_b2, ms_wd, ms_gd, ms_bd,
      P, spat_msb);
  fsum_kernel<<<50, 256, 0, stream>>>(x_enc, xs);
  spat_kernel<<<200, 256, 0, stream>>>(spat_msb, xs, sf_w, sf_b, ybuf);
  cf_mix_kernel<<<200, 64, 0, stream>>>(P, cf_cw_w, cf_cw_b, cf_dw, cf_db, cfb);
  chan_partial_kernel<<<640, 320, 0, stream>>>(x_enc, cfb, partial);
  chan_reduce_kernel<<<200, 256, 0, stream>>>(partial, ybuf);
  dconv1_kernel<<<96, 256, 0, stream>>>(ybuf, dp_c1w, dr_c1w, dp_c1b, d1);
  dconv2_kernel<<<256, 320, 0, stream>>>(d1, dp_c2w, dr_c2w, dp_c2b, flat);
  lin_kernel<<<578, 256, 0, stream>>>(flat, dp_l1w, dr_l1w, dp_l1b, l1o, NLIN);
  lin_kernel<<<289, 256, 0, stream>>>(l1o, dp_l2w, dr_l2w, dp_l2b, l2o, NL2);
  lin3_kernel<<<1, 1024, 0, stream>>>(l2o, dp_l3w, dr_l3w, dp_l3b, (float*)d_out);
}